// Round 1
// baseline (749.653 us; speedup 1.0000x reference)
//
#include <hip/hip_runtime.h>
#include <hip/hip_bf16.h>

#define HID 768
#define NHEADS 12
#define HD 64
#define INTER 1152
#define SEQ 2048
#define NB 2
#define WIN 64        // half-window: |i-j| <= 64
#define QT 32         // queries per attention block
#define KT 160        // key window per block: QT + 2*WIN

__device__ __forceinline__ float bf2f(unsigned short u) {
    union { unsigned int i; float f; } c; c.i = ((unsigned int)u) << 16; return c.f;
}
__device__ __forceinline__ unsigned short f2bf(float f) {
    union { float f; unsigned int i; } c; c.f = f;
    unsigned int b = c.i;
    b += 0x7FFFu + ((b >> 16) & 1u);   // round-to-nearest-even
    return (unsigned short)(b >> 16);
}

// ---------------- RMSNorm: one block per row (768 cols) ----------------
__global__ __launch_bounds__(256) void rmsnorm_kernel(const float* __restrict__ x,
                                                      const float* __restrict__ g,
                                                      float* __restrict__ out) {
    int row = blockIdx.x;
    const float* xr = x + (size_t)row * HID;
    float* orow = out + (size_t)row * HID;
    int tid = threadIdx.x;
    float v0 = xr[tid], v1 = xr[tid + 256], v2 = xr[tid + 512];
    float s = v0 * v0 + v1 * v1 + v2 * v2;
    #pragma unroll
    for (int m = 32; m >= 1; m >>= 1) s += __shfl_xor(s, m, 64);
    __shared__ float red[4];
    if ((tid & 63) == 0) red[tid >> 6] = s;
    __syncthreads();
    float tot = red[0] + red[1] + red[2] + red[3];
    float inv = rsqrtf(tot * (1.0f / HID) + 1e-5f);
    orow[tid]       = v0 * inv * g[tid];
    orow[tid + 256] = v1 * inv * g[tid + 256];
    orow[tid + 512] = v2 * inv * g[tid + 512];
}

// ---------------- fp32 tiled GEMM: C[M,N] = A[M,K] @ B[K,N] (+resid) ----
// 64x64 tile, BK=16, 256 threads, 4x4 per thread.
__global__ __launch_bounds__(256) void gemm_kernel(const float* __restrict__ A,
                                                   const float* __restrict__ B,
                                                   const float* __restrict__ resid,
                                                   float* __restrict__ C,
                                                   int N, int K) {
    __shared__ float As[16][64];   // As[k][m]
    __shared__ float Bs[16][64];   // Bs[k][n]
    int row0 = blockIdx.y * 64, col0 = blockIdx.x * 64;
    int tid = threadIdx.x;
    int tx = tid & 15, ty = tid >> 4;
    int ar = tid >> 2, ac = (tid & 3) << 2;   // A: 64 rows x 16 k, float4 along k
    int br = tid >> 4, bc = (tid & 15) << 2;  // B: 16 k x 64 cols, float4 along n
    float acc[4][4] = {};
    for (int k0 = 0; k0 < K; k0 += 16) {
        float4 av = *reinterpret_cast<const float4*>(&A[(size_t)(row0 + ar) * K + k0 + ac]);
        float4 bv = *reinterpret_cast<const float4*>(&B[(size_t)(k0 + br) * N + col0 + bc]);
        As[ac + 0][ar] = av.x; As[ac + 1][ar] = av.y; As[ac + 2][ar] = av.z; As[ac + 3][ar] = av.w;
        *reinterpret_cast<float4*>(&Bs[br][bc]) = bv;
        __syncthreads();
        #pragma unroll
        for (int kk = 0; kk < 16; ++kk) {
            float ax[4], bx[4];
            *reinterpret_cast<float4*>(ax) = *reinterpret_cast<const float4*>(&As[kk][ty << 2]);
            *reinterpret_cast<float4*>(bx) = *reinterpret_cast<const float4*>(&Bs[kk][tx << 2]);
            #pragma unroll
            for (int i = 0; i < 4; ++i)
                #pragma unroll
                for (int j = 0; j < 4; ++j)
                    acc[i][j] += ax[i] * bx[j];
        }
        __syncthreads();
    }
    #pragma unroll
    for (int i = 0; i < 4; ++i) {
        size_t r = row0 + (ty << 2) + i;
        size_t cbase = r * N + col0 + (tx << 2);
        float4 o;
        o.x = acc[i][0]; o.y = acc[i][1]; o.z = acc[i][2]; o.w = acc[i][3];
        if (resid) {
            float4 rv = *reinterpret_cast<const float4*>(&resid[cbase]);
            o.x += rv.x; o.y += rv.y; o.z += rv.z; o.w += rv.w;
        }
        *reinterpret_cast<float4*>(&C[cbase]) = o;
    }
}

// ---------------- RoPE in-place on q,k inside qkv [4096, 2304] ----------
__global__ __launch_bounds__(256) void rope_kernel(float* __restrict__ qkv) {
    int row = blockIdx.x;            // b*SEQ + s
    int s = row & (SEQ - 1);
    int tid = threadIdx.x;
    float* base = qkv + (size_t)row * 2304;
    float vals[2][3], prt[2][3];
    #pragma unroll
    for (int p = 0; p < 2; ++p)
        #pragma unroll
        for (int i = 0; i < 3; ++i) {
            int e = tid + i * 256;
            vals[p][i] = base[p * 768 + e];
            prt[p][i]  = base[p * 768 + (e ^ 32)];
        }
    __syncthreads();   // all reads done before any in-place write
    #pragma unroll
    for (int p = 0; p < 2; ++p)
        #pragma unroll
        for (int i = 0; i < 3; ++i) {
            int e = tid + i * 256;
            int d = e & 63;
            int fi = d & 31;
            // inv_freq = 10000^(-fi/32) ; log2(10000)/32 = 0.41524101186
            float freq = (float)s * exp2f(-(float)fi * 0.41524101186f);
            float sn, c;
            sincosf(freq, &sn, &c);
            float sign = (d < 32) ? -1.f : 1.f;
            base[p * 768 + e] = vals[p][i] * c + sign * prt[p][i] * sn;
        }
}

// ---------------- Sliding-window attention --------------------------------
// block = (b, head, 32-query tile); 256 threads = 4 waves, 8 queries/wave.
__global__ __launch_bounds__(256) void attn_kernel(const float* __restrict__ qkv,
                                                   const int* __restrict__ pmask,
                                                   float* __restrict__ ao) {
    __shared__ unsigned short Ksh[KT][68];  // bf16, padded (bank spread)
    __shared__ unsigned short Vsh[KT][64];  // bf16, unpadded (d-consecutive reads)
    __shared__ float Qs[QT][64];
    __shared__ float Ps[4][192];
    int bid = blockIdx.x;
    int qt = bid & 63;                 // SEQ/QT = 64
    int h = (bid >> 6) % NHEADS;
    int b = bid / (64 * NHEADS);
    int q0 = qt * QT;
    int kstart = q0 - WIN;             // may be negative
    int tid = threadIdx.x;

    for (int it = 0; it < (KT * 64) / 256; ++it) {   // 40 iters
        int lin = it * 256 + tid;
        int kj = lin >> 6, d = lin & 63;
        int sk = kstart + kj;
        float kv = 0.f, vv = 0.f;
        if (sk >= 0 && sk < SEQ) {
            size_t base = ((size_t)(b * SEQ + sk)) * 2304 + h * 64 + d;
            kv = qkv[base + 768];
            vv = qkv[base + 1536];
        }
        Ksh[kj][d] = f2bf(kv);
        Vsh[kj][d] = f2bf(vv);
    }
    for (int it = 0; it < (QT * 64) / 256; ++it) {   // 8 iters
        int lin = it * 256 + tid;
        int qi = lin >> 6, d = lin & 63;
        Qs[qi][d] = qkv[((size_t)(b * SEQ + q0 + qi)) * 2304 + h * 64 + d];
    }
    __syncthreads();

    int w = tid >> 6, lane = tid & 63;
    for (int qq = 0; qq < 8; ++qq) {
        int qi = w * 8 + qq;
        int q = q0 + qi;
        float sc[3];
        #pragma unroll
        for (int it = 0; it < 3; ++it) {
            int kj = it * 64 + lane;
            int sk = kstart + kj;
            float s = -1e30f;
            if (kj < KT && sk >= 0 && sk < SEQ && sk >= q - WIN && sk <= q + WIN) {
                const float4* qv = reinterpret_cast<const float4*>(Qs[qi]);
                const ushort4* kvp = reinterpret_cast<const ushort4*>(&Ksh[kj][0]);
                float acc = 0.f;
                #pragma unroll
                for (int d4 = 0; d4 < 16; ++d4) {
                    float4 qf = qv[d4];
                    ushort4 kk = kvp[d4];
                    acc += qf.x * bf2f(kk.x) + qf.y * bf2f(kk.y)
                         + qf.z * bf2f(kk.z) + qf.w * bf2f(kk.w);
                }
                s = acc * 0.125f;   // 1/sqrt(64)
                s += (1.0f - (float)pmask[b * SEQ + sk]) * -1e9f;
            }
            sc[it] = s;
        }
        float m = fmaxf(sc[0], fmaxf(sc[1], sc[2]));
        #pragma unroll
        for (int mm = 32; mm >= 1; mm >>= 1) m = fmaxf(m, __shfl_xor(m, mm, 64));
        float ssum = 0.f;
        float e[3];
        #pragma unroll
        for (int it = 0; it < 3; ++it) {
            e[it] = (sc[it] > -1e29f) ? expf(sc[it] - m) : 0.f;
            ssum += e[it];
        }
        #pragma unroll
        for (int mm = 32; mm >= 1; mm >>= 1) ssum += __shfl_xor(ssum, mm, 64);
        #pragma unroll
        for (int it = 0; it < 3; ++it) Ps[w][it * 64 + lane] = e[it];
        __syncthreads();   // uniform (8 iters per wave); orders Ps writes vs reads
        float oacc = 0.f;
        #pragma unroll 8
        for (int kj = 0; kj < KT; ++kj) oacc += Ps[w][kj] * bf2f(Vsh[kj][lane]);
        float invs = 1.0f / fmaxf(ssum, 1e-30f);
        ao[((size_t)(b * SEQ + q)) * HID + h * 64 + lane] = oacc * invs;
        __syncthreads();
    }
}

// ---------------- gated GELU: a = gelu_tanh(a) * b ------------------------
__global__ __launch_bounds__(256) void gelumul_kernel(float4* __restrict__ a,
                                                      const float4* __restrict__ b) {
    int i = blockIdx.x * 256 + threadIdx.x;
    float4 va = a[i], vb = b[i];
    float r[4] = {va.x, va.y, va.z, va.w};
    float m[4] = {vb.x, vb.y, vb.z, vb.w};
    #pragma unroll
    for (int j = 0; j < 4; ++j) {
        float xa = r[j];
        float t = tanhf(0.7978845608028654f * (xa + 0.044715f * xa * xa * xa));
        r[j] = 0.5f * xa * (1.f + t) * m[j];
    }
    va.x = r[0]; va.y = r[1]; va.z = r[2]; va.w = r[3];
    a[i] = va;
}

extern "C" void kernel_launch(void* const* d_in, const int* in_sizes, int n_in,
                              void* d_out, int out_size, void* d_ws, size_t ws_size,
                              hipStream_t stream) {
    const float* x       = (const float*)d_in[0];
    const int*   pmask   = (const int*)d_in[1];
    const float* wqkv    = (const float*)d_in[2];
    const float* wo_attn = (const float*)d_in[3];
    const float* wi0     = (const float*)d_in[4];
    const float* wi1     = (const float*)d_in[5];
    const float* wo_mlp  = (const float*)d_in[6];
    const float* g_attn  = (const float*)d_in[7];
    const float* g_mlp   = (const float*)d_in[8];
    float* out = (float*)d_out;
    float* ws  = (float*)d_ws;

    const int ROWS = NB * SEQ;                 // 4096
    float* h    = ws;                          // 4096*768
    float* qkvb = h + (size_t)ROWS * HID;      // 4096*2304
    float* ao   = qkvb + (size_t)ROWS * 2304;  // 4096*768
    float* ma   = qkvb;                        // alias: qkv dead after attention
    float* mb   = qkvb + (size_t)ROWS * INTER;

    // 1. h = rmsnorm(x, g_attn)
    rmsnorm_kernel<<<ROWS, 256, 0, stream>>>(x, g_attn, h);
    // 2. qkv = h @ wqkv
    gemm_kernel<<<dim3(2304 / 64, ROWS / 64), 256, 0, stream>>>(h, wqkv, nullptr, qkvb, 2304, HID);
    // 3. RoPE on q,k in-place
    rope_kernel<<<ROWS, 256, 0, stream>>>(qkvb);
    // 4. sliding-window attention -> ao
    attn_kernel<<<NB * NHEADS * (SEQ / QT), 256, 0, stream>>>(qkvb, pmask, ao);
    // 5. x1 = x + ao @ wo_attn   (store into d_out)
    gemm_kernel<<<dim3(HID / 64, ROWS / 64), 256, 0, stream>>>(ao, wo_attn, x, out, HID, HID);
    // 6. h = rmsnorm(x1, g_mlp)
    rmsnorm_kernel<<<ROWS, 256, 0, stream>>>(out, g_mlp, h);
    // 7/8. ma = h @ wi0 ; mb = h @ wi1
    gemm_kernel<<<dim3(INTER / 64, ROWS / 64), 256, 0, stream>>>(h, wi0, nullptr, ma, INTER, HID);
    gemm_kernel<<<dim3(INTER / 64, ROWS / 64), 256, 0, stream>>>(h, wi1, nullptr, mb, INTER, HID);
    // 9. ma = gelu(ma) * mb
    gelumul_kernel<<<(ROWS * INTER / 4) / 256, 256, 0, stream>>>((float4*)ma, (const float4*)mb);
    // 10. out = x1 + ma @ wo_mlp  (resid aliases C; per-element read-then-write)
    gemm_kernel<<<dim3(HID / 64, ROWS / 64), 256, 0, stream>>>(ma, wo_mlp, out, out, HID, INTER);
}

// Round 2
// 338.328 us; speedup vs baseline: 2.2158x; 2.2158x over previous
//
#include <hip/hip_runtime.h>
#include <hip/hip_bf16.h>

#define HID 768
#define NHEADS 12
#define HD 64
#define INTER 1152
#define SEQ 2048
#define NB 2
#define ROWS (NB * SEQ)   // 4096
#define WIN 64            // half-window: |i-j| <= 64
#define QT 32             // queries per attention block
#define KT 160            // key window per block: QT + 2*WIN

typedef __attribute__((ext_vector_type(8))) short bf16x8;
typedef __attribute__((ext_vector_type(4))) float f32x4;

__device__ __forceinline__ float bf2f(unsigned short u) {
    union { unsigned int i; float f; } c; c.i = ((unsigned int)u) << 16; return c.f;
}
__device__ __forceinline__ unsigned short f2bf(float f) {
    union { float f; unsigned int i; } c; c.f = f;
    unsigned int b = c.i;
    b += 0x7FFFu + ((b >> 16) & 1u);   // round-to-nearest-even
    return (unsigned short)(b >> 16);
}
__device__ __forceinline__ void gload16(const void* g, void* l) {
    __builtin_amdgcn_global_load_lds((const __attribute__((address_space(1))) unsigned int*)g,
                                     (__attribute__((address_space(3))) unsigned int*)l,
                                     16, 0, 0);
}

// ---------------- RMSNorm: one block per row (768 cols), bf16 out --------
__global__ __launch_bounds__(256) void rmsnorm_kernel(const float* __restrict__ x,
                                                      const float* __restrict__ g,
                                                      unsigned short* __restrict__ out) {
    int row = blockIdx.x;
    const float* xr = x + (size_t)row * HID;
    unsigned short* orow = out + (size_t)row * HID;
    int tid = threadIdx.x;
    float v0 = xr[tid], v1 = xr[tid + 256], v2 = xr[tid + 512];
    float s = v0 * v0 + v1 * v1 + v2 * v2;
    #pragma unroll
    for (int m = 32; m >= 1; m >>= 1) s += __shfl_xor(s, m, 64);
    __shared__ float red[4];
    if ((tid & 63) == 0) red[tid >> 6] = s;
    __syncthreads();
    float tot = red[0] + red[1] + red[2] + red[3];
    float inv = rsqrtf(tot * (1.0f / HID) + 1e-5f);
    orow[tid]       = f2bf(v0 * inv * g[tid]);
    orow[tid + 256] = f2bf(v1 * inv * g[tid + 256]);
    orow[tid + 512] = f2bf(v2 * inv * g[tid + 512]);
}

// ------------- weight transpose+convert: W[K][N] fp32 -> Wt[N][K] bf16 ---
__global__ __launch_bounds__(256) void wt_kernel(const float* __restrict__ W,
                                                 unsigned short* __restrict__ Wt,
                                                 int K, int N) {
    __shared__ float t[32][33];
    int bx = blockIdx.x * 32;   // n tile
    int by = blockIdx.y * 32;   // k tile
    int tx = threadIdx.x & 31, ty = threadIdx.x >> 5;
    #pragma unroll
    for (int i = 0; i < 4; ++i)
        t[ty + i * 8][tx] = W[(size_t)(by + ty + i * 8) * N + bx + tx];
    __syncthreads();
    #pragma unroll
    for (int i = 0; i < 4; ++i)
        Wt[(size_t)(bx + ty + i * 8) * K + by + tx] = f2bf(t[tx][ty + i * 8]);
}

// ---------------- bf16 MFMA GEMM: C[M,N] = A[M,K] @ Bt[N,K]^T (+resid) ---
// 128x128 tile, BK=32, 256 threads = 4 waves (2x2), 4x4 16x16x32 frags/wave.
__global__ __launch_bounds__(256) void mfma_gemm(const unsigned short* __restrict__ A,
                                                 const unsigned short* __restrict__ Bt,
                                                 const float* __restrict__ resid,
                                                 float* __restrict__ C,
                                                 int N, int K) {
    __shared__ unsigned short As[128 * 32];
    __shared__ unsigned short Bs[128 * 32];
    int tid = threadIdx.x;
    int wave = tid >> 6, lane = tid & 63;
    int row0 = blockIdx.y * 128, col0 = blockIdx.x * 128;
    int wr = wave >> 1, wc = wave & 1;
    int fr = lane & 15, fq = lane >> 4;

    f32x4 acc[4][4];
    #pragma unroll
    for (int m = 0; m < 4; ++m)
        #pragma unroll
        for (int n = 0; n < 4; ++n)
            acc[m][n] = (f32x4){0.f, 0.f, 0.f, 0.f};

    // staging geometry: tile = 8192 B = 2 calls x 4 waves x (64 lanes x 16 B)
    // linear byte offset L = c*4096 + wave*1024 + lane*16 ; row=L>>6, colb=L&63
    const size_t strideA = (size_t)K * 2;   // bytes per A row
    const char* Ab = (const char*)A;
    const char* Bb = (const char*)Bt;

    for (int k0 = 0; k0 < K; k0 += 32) {
        #pragma unroll
        for (int c = 0; c < 2; ++c) {
            int L = c * 4096 + wave * 1024 + lane * 16;
            int r = L >> 6, cb = L & 63;
            gload16(Ab + (size_t)(row0 + r) * strideA + (size_t)k0 * 2 + cb,
                    (char*)As + c * 4096 + wave * 1024);
            gload16(Bb + (size_t)(col0 + r) * strideA + (size_t)k0 * 2 + cb,
                    (char*)Bs + c * 4096 + wave * 1024);
        }
        __syncthreads();
        bf16x8 af[4], bfr[4];
        #pragma unroll
        for (int m = 0; m < 4; ++m)
            af[m] = *(const bf16x8*)&As[(wr * 64 + m * 16 + fr) * 32 + fq * 8];
        #pragma unroll
        for (int n = 0; n < 4; ++n)
            bfr[n] = *(const bf16x8*)&Bs[(wc * 64 + n * 16 + fr) * 32 + fq * 8];
        #pragma unroll
        for (int m = 0; m < 4; ++m)
            #pragma unroll
            for (int n = 0; n < 4; ++n)
                acc[m][n] = __builtin_amdgcn_mfma_f32_16x16x32_bf16(af[m], bfr[n], acc[m][n], 0, 0, 0);
        __syncthreads();
    }

    // C/D layout: col = lane&15, row = (lane>>4)*4 + j   [m89/m91 verified]
    #pragma unroll
    for (int m = 0; m < 4; ++m) {
        #pragma unroll
        for (int j = 0; j < 4; ++j) {
            size_t r = (size_t)(row0 + wr * 64 + m * 16 + fq * 4 + j);
            #pragma unroll
            for (int n = 0; n < 4; ++n) {
                size_t idx = r * N + (col0 + wc * 64 + n * 16 + fr);
                float v = acc[m][n][j];
                if (resid) v += resid[idx];
                C[idx] = v;
            }
        }
    }
}

// ---------------- RoPE in-place on q,k inside qkv [4096, 2304] ----------
__global__ __launch_bounds__(256) void rope_kernel(float* __restrict__ qkv) {
    int row = blockIdx.x;            // b*SEQ + s
    int s = row & (SEQ - 1);
    int tid = threadIdx.x;
    float* base = qkv + (size_t)row * 2304;
    float vals[2][3], prt[2][3];
    #pragma unroll
    for (int p = 0; p < 2; ++p)
        #pragma unroll
        for (int i = 0; i < 3; ++i) {
            int e = tid + i * 256;
            vals[p][i] = base[p * 768 + e];
            prt[p][i]  = base[p * 768 + (e ^ 32)];
        }
    __syncthreads();   // all reads done before any in-place write
    #pragma unroll
    for (int p = 0; p < 2; ++p)
        #pragma unroll
        for (int i = 0; i < 3; ++i) {
            int e = tid + i * 256;
            int d = e & 63;
            int fi = d & 31;
            float freq = (float)s * exp2f(-(float)fi * 0.41524101186f);
            float sn, c;
            sincosf(freq, &sn, &c);
            float sign = (d < 32) ? -1.f : 1.f;
            base[p * 768 + e] = vals[p][i] * c + sign * prt[p][i] * sn;
        }
}

// ---------------- Sliding-window attention (bf16 out) ---------------------
__global__ __launch_bounds__(256) void attn_kernel(const float* __restrict__ qkv,
                                                   const int* __restrict__ pmask,
                                                   unsigned short* __restrict__ ao) {
    __shared__ unsigned short Ksh[KT][68];
    __shared__ unsigned short Vsh[KT][64];
    __shared__ float Qs[QT][64];
    __shared__ float Ps[4][192];
    int bid = blockIdx.x;
    int qt = bid & 63;
    int h = (bid >> 6) % NHEADS;
    int b = bid / (64 * NHEADS);
    int q0 = qt * QT;
    int kstart = q0 - WIN;
    int tid = threadIdx.x;

    for (int it = 0; it < (KT * 64) / 256; ++it) {
        int lin = it * 256 + tid;
        int kj = lin >> 6, d = lin & 63;
        int sk = kstart + kj;
        float kv = 0.f, vv = 0.f;
        if (sk >= 0 && sk < SEQ) {
            size_t base = ((size_t)(b * SEQ + sk)) * 2304 + h * 64 + d;
            kv = qkv[base + 768];
            vv = qkv[base + 1536];
        }
        Ksh[kj][d] = f2bf(kv);
        Vsh[kj][d] = f2bf(vv);
    }
    for (int it = 0; it < (QT * 64) / 256; ++it) {
        int lin = it * 256 + tid;
        int qi = lin >> 6, d = lin & 63;
        Qs[qi][d] = qkv[((size_t)(b * SEQ + q0 + qi)) * 2304 + h * 64 + d];
    }
    __syncthreads();

    int w = tid >> 6, lane = tid & 63;
    for (int qq = 0; qq < 8; ++qq) {
        int qi = w * 8 + qq;
        int q = q0 + qi;
        float sc[3];
        #pragma unroll
        for (int it = 0; it < 3; ++it) {
            int kj = it * 64 + lane;
            int sk = kstart + kj;
            float s = -1e30f;
            if (kj < KT && sk >= 0 && sk < SEQ && sk >= q - WIN && sk <= q + WIN) {
                const float4* qv = reinterpret_cast<const float4*>(Qs[qi]);
                const ushort4* kvp = reinterpret_cast<const ushort4*>(&Ksh[kj][0]);
                float acc = 0.f;
                #pragma unroll
                for (int d4 = 0; d4 < 16; ++d4) {
                    float4 qf = qv[d4];
                    ushort4 kk = kvp[d4];
                    acc += qf.x * bf2f(kk.x) + qf.y * bf2f(kk.y)
                         + qf.z * bf2f(kk.z) + qf.w * bf2f(kk.w);
                }
                s = acc * 0.125f;
                s += (1.0f - (float)pmask[b * SEQ + sk]) * -1e9f;
            }
            sc[it] = s;
        }
        float m = fmaxf(sc[0], fmaxf(sc[1], sc[2]));
        #pragma unroll
        for (int mm = 32; mm >= 1; mm >>= 1) m = fmaxf(m, __shfl_xor(m, mm, 64));
        float ssum = 0.f;
        float e[3];
        #pragma unroll
        for (int it = 0; it < 3; ++it) {
            e[it] = (sc[it] > -1e29f) ? expf(sc[it] - m) : 0.f;
            ssum += e[it];
        }
        #pragma unroll
        for (int mm = 32; mm >= 1; mm >>= 1) ssum += __shfl_xor(ssum, mm, 64);
        #pragma unroll
        for (int it = 0; it < 3; ++it) Ps[w][it * 64 + lane] = e[it];
        __syncthreads();
        float oacc = 0.f;
        #pragma unroll 8
        for (int kj = 0; kj < KT; ++kj) oacc += Ps[w][kj] * bf2f(Vsh[kj][lane]);
        float invs = 1.0f / fmaxf(ssum, 1e-30f);
        ao[((size_t)(b * SEQ + q)) * HID + h * 64 + lane] = f2bf(oacc * invs);
        __syncthreads();
    }
}

// ---------------- gated GELU: out_bf16 = gelu_tanh(a) * b -----------------
__global__ __launch_bounds__(256) void gelumul_kernel(const float4* __restrict__ a,
                                                      const float4* __restrict__ b,
                                                      ushort4* __restrict__ o) {
    int i = blockIdx.x * 256 + threadIdx.x;
    float4 va = a[i], vb = b[i];
    float r[4] = {va.x, va.y, va.z, va.w};
    float m[4] = {vb.x, vb.y, vb.z, vb.w};
    unsigned short p[4];
    #pragma unroll
    for (int j = 0; j < 4; ++j) {
        float xa = r[j];
        float t = tanhf(0.7978845608028654f * (xa + 0.044715f * xa * xa * xa));
        p[j] = f2bf(0.5f * xa * (1.f + t) * m[j]);
    }
    ushort4 ov; ov.x = p[0]; ov.y = p[1]; ov.z = p[2]; ov.w = p[3];
    o[i] = ov;
}

extern "C" void kernel_launch(void* const* d_in, const int* in_sizes, int n_in,
                              void* d_out, int out_size, void* d_ws, size_t ws_size,
                              hipStream_t stream) {
    const float* x       = (const float*)d_in[0];
    const int*   pmask   = (const int*)d_in[1];
    const float* wqkv    = (const float*)d_in[2];
    const float* wo_attn = (const float*)d_in[3];
    const float* wi0     = (const float*)d_in[4];
    const float* wi1     = (const float*)d_in[5];
    const float* wo_mlp  = (const float*)d_in[6];
    const float* g_attn  = (const float*)d_in[7];
    const float* g_mlp   = (const float*)d_in[8];
    float* out = (float*)d_out;

    char* w = (char*)d_ws;
    unsigned short* hbf  = (unsigned short*)w;                    // 4096*768 bf16
    unsigned short* aobf = (unsigned short*)(w + 6291456);        // 4096*768 bf16
    float* qkvb = (float*)(w + 12582912);                         // 4096*2304 fp32
    float* ma   = qkvb;                                           // alias after attn
    float* mb   = qkvb + (size_t)ROWS * INTER;
    char* wts = w + 12582912 + 37748736;
    unsigned short* wqkvT = (unsigned short*)(wts);               // [2304][768]
    unsigned short* woaT  = (unsigned short*)(wts + 3538944);     // [768][768]
    unsigned short* wi0T  = (unsigned short*)(wts + 3538944 + 1179648);
    unsigned short* wi1T  = (unsigned short*)(wts + 3538944 + 1179648 + 1769472);
    unsigned short* womT  = (unsigned short*)(wts + 3538944 + 1179648 + 2 * 1769472);
    unsigned short* mgate = (unsigned short*)w;                   // alias h+ao, 4096*1152

    // 0. weight transpose+convert (fp32 [K][N] -> bf16 [N][K])
    wt_kernel<<<dim3(2304 / 32, 768 / 32), 256, 0, stream>>>(wqkv, wqkvT, 768, 2304);
    wt_kernel<<<dim3(768 / 32, 768 / 32), 256, 0, stream>>>(wo_attn, woaT, 768, 768);
    wt_kernel<<<dim3(1152 / 32, 768 / 32), 256, 0, stream>>>(wi0, wi0T, 768, 1152);
    wt_kernel<<<dim3(1152 / 32, 768 / 32), 256, 0, stream>>>(wi1, wi1T, 768, 1152);
    wt_kernel<<<dim3(768 / 32, 1152 / 32), 256, 0, stream>>>(wo_mlp, womT, 1152, 768);

    // 1. h = rmsnorm(x, g_attn)  (bf16)
    rmsnorm_kernel<<<ROWS, 256, 0, stream>>>(x, g_attn, hbf);
    // 2. qkv = h @ wqkv  (fp32 out)
    mfma_gemm<<<dim3(2304 / 128, ROWS / 128), 256, 0, stream>>>(hbf, wqkvT, nullptr, qkvb, 2304, 768);
    // 3. RoPE on q,k in-place
    rope_kernel<<<ROWS, 256, 0, stream>>>(qkvb);
    // 4. sliding-window attention -> ao (bf16)
    attn_kernel<<<NB * NHEADS * (SEQ / QT), 256, 0, stream>>>(qkvb, pmask, aobf);
    // 5. x1 = x + ao @ wo_attn   (store into d_out)
    mfma_gemm<<<dim3(768 / 128, ROWS / 128), 256, 0, stream>>>(aobf, woaT, x, out, 768, 768);
    // 6. h = rmsnorm(x1, g_mlp)  (bf16)
    rmsnorm_kernel<<<ROWS, 256, 0, stream>>>(out, g_mlp, hbf);
    // 7/8. ma = h @ wi0 ; mb = h @ wi1  (fp32)
    mfma_gemm<<<dim3(INTER / 128, ROWS / 128), 256, 0, stream>>>(hbf, wi0T, nullptr, ma, INTER, 768);
    mfma_gemm<<<dim3(INTER / 128, ROWS / 128), 256, 0, stream>>>(hbf, wi1T, nullptr, mb, INTER, 768);
    // 9. mgate = gelu(ma) * mb  (bf16)
    gelumul_kernel<<<(ROWS * INTER / 4) / 256, 256, 0, stream>>>((const float4*)ma, (const float4*)mb, (ushort4*)mgate);
    // 10. out = x1 + mgate @ wo_mlp
    mfma_gemm<<<dim3(768 / 128, ROWS / 128), 256, 0, stream>>>(mgate, womT, out, out, 768, 1152);
}

// Round 3
// 214.030 us; speedup vs baseline: 3.5026x; 1.5807x over previous
//
#include <hip/hip_runtime.h>
#include <hip/hip_bf16.h>

#define HID 768
#define NHEADS 12
#define HD 64
#define INTER 1152
#define SEQ 2048
#define NB 2
#define ROWS (NB * SEQ)   // 4096
#define QTA 64            // queries per attention block
#define KTA 192           // key panel: QTA + 2*64

typedef __attribute__((ext_vector_type(8))) short bf16x8;
typedef __attribute__((ext_vector_type(4))) float f32x4;

__device__ __forceinline__ float bf2f(unsigned short u) {
    union { unsigned int i; float f; } c; c.i = ((unsigned int)u) << 16; return c.f;
}
__device__ __forceinline__ unsigned short f2bf(float f) {
    union { float f; unsigned int i; } c; c.f = f;
    unsigned int b = c.i;
    b += 0x7FFFu + ((b >> 16) & 1u);   // round-to-nearest-even
    return (unsigned short)(b >> 16);
}
__device__ __forceinline__ void gload16(const void* g, void* l) {
    __builtin_amdgcn_global_load_lds((const __attribute__((address_space(1))) unsigned int*)g,
                                     (__attribute__((address_space(3))) unsigned int*)l,
                                     16, 0, 0);
}

// ---------------- RMSNorm: one block per row (768 cols), bf16 out --------
__global__ __launch_bounds__(256) void rmsnorm_kernel(const float* __restrict__ x,
                                                      const float* __restrict__ g,
                                                      unsigned short* __restrict__ out) {
    int row = blockIdx.x;
    const float* xr = x + (size_t)row * HID;
    unsigned short* orow = out + (size_t)row * HID;
    int tid = threadIdx.x;
    float v0 = xr[tid], v1 = xr[tid + 256], v2 = xr[tid + 512];
    float s = v0 * v0 + v1 * v1 + v2 * v2;
    #pragma unroll
    for (int m = 32; m >= 1; m >>= 1) s += __shfl_xor(s, m, 64);
    __shared__ float red[4];
    if ((tid & 63) == 0) red[tid >> 6] = s;
    __syncthreads();
    float tot = red[0] + red[1] + red[2] + red[3];
    float inv = rsqrtf(tot * (1.0f / HID) + 1e-5f);
    orow[tid]       = f2bf(v0 * inv * g[tid]);
    orow[tid + 256] = f2bf(v1 * inv * g[tid + 256]);
    orow[tid + 512] = f2bf(v2 * inv * g[tid + 512]);
}

// ------------- weight transpose+convert: W[K][N] fp32 -> Wt[N][K] bf16 ---
__global__ __launch_bounds__(256) void wt_kernel(const float* __restrict__ W,
                                                 unsigned short* __restrict__ Wt,
                                                 int K, int N) {
    __shared__ float t[32][33];
    int bx = blockIdx.x * 32;   // n tile
    int by = blockIdx.y * 32;   // k tile
    int tx = threadIdx.x & 31, ty = threadIdx.x >> 5;
    #pragma unroll
    for (int i = 0; i < 4; ++i)
        t[ty + i * 8][tx] = W[(size_t)(by + ty + i * 8) * N + bx + tx];
    __syncthreads();
    #pragma unroll
    for (int i = 0; i < 4; ++i)
        Wt[(size_t)(bx + ty + i * 8) * K + by + tx] = f2bf(t[tx][ty + i * 8]);
}

// ---------------- bf16 MFMA GEMM: C[M,N] = A[M,K] @ Bt[N,K]^T (+resid) ---
__global__ __launch_bounds__(256) void mfma_gemm(const unsigned short* __restrict__ A,
                                                 const unsigned short* __restrict__ Bt,
                                                 const float* __restrict__ resid,
                                                 float* __restrict__ C,
                                                 int N, int K) {
    __shared__ unsigned short As[128 * 32];
    __shared__ unsigned short Bs[128 * 32];
    int tid = threadIdx.x;
    int wave = tid >> 6, lane = tid & 63;
    int row0 = blockIdx.y * 128, col0 = blockIdx.x * 128;
    int wr = wave >> 1, wc = wave & 1;
    int fr = lane & 15, fq = lane >> 4;

    f32x4 acc[4][4];
    #pragma unroll
    for (int m = 0; m < 4; ++m)
        #pragma unroll
        for (int n = 0; n < 4; ++n)
            acc[m][n] = (f32x4){0.f, 0.f, 0.f, 0.f};

    const size_t strideA = (size_t)K * 2;
    const char* Ab = (const char*)A;
    const char* Bb = (const char*)Bt;

    for (int k0 = 0; k0 < K; k0 += 32) {
        #pragma unroll
        for (int c = 0; c < 2; ++c) {
            int L = c * 4096 + wave * 1024 + lane * 16;
            int r = L >> 6, cb = L & 63;
            gload16(Ab + (size_t)(row0 + r) * strideA + (size_t)k0 * 2 + cb,
                    (char*)As + c * 4096 + wave * 1024);
            gload16(Bb + (size_t)(col0 + r) * strideA + (size_t)k0 * 2 + cb,
                    (char*)Bs + c * 4096 + wave * 1024);
        }
        __syncthreads();
        bf16x8 af[4], bfr[4];
        #pragma unroll
        for (int m = 0; m < 4; ++m)
            af[m] = *(const bf16x8*)&As[(wr * 64 + m * 16 + fr) * 32 + fq * 8];
        #pragma unroll
        for (int n = 0; n < 4; ++n)
            bfr[n] = *(const bf16x8*)&Bs[(wc * 64 + n * 16 + fr) * 32 + fq * 8];
        #pragma unroll
        for (int m = 0; m < 4; ++m)
            #pragma unroll
            for (int n = 0; n < 4; ++n)
                acc[m][n] = __builtin_amdgcn_mfma_f32_16x16x32_bf16(af[m], bfr[n], acc[m][n], 0, 0, 0);
        __syncthreads();
    }

    #pragma unroll
    for (int m = 0; m < 4; ++m) {
        #pragma unroll
        for (int j = 0; j < 4; ++j) {
            size_t r = (size_t)(row0 + wr * 64 + m * 16 + fq * 4 + j);
            #pragma unroll
            for (int n = 0; n < 4; ++n) {
                size_t idx = r * N + (col0 + wc * 64 + n * 16 + fr);
                float v = acc[m][n][j];
                if (resid) v += resid[idx];
                C[idx] = v;
            }
        }
    }
}

// -------- qkvprep: fp32 qkv -> RoPE'd bf16 Q,K [B,H,S,64] + V^T [B,H,64,S]
__global__ __launch_bounds__(256) void qkvprep(const float* __restrict__ qkvb,
                                               unsigned short* __restrict__ Qb,
                                               unsigned short* __restrict__ Kb,
                                               unsigned short* __restrict__ Vt) {
    __shared__ float tv[64][65];
    int bid = blockIdx.x;
    int st = bid & 31;
    int h  = (bid >> 5) % NHEADS;
    int b  = bid / (32 * NHEADS);
    int bh = b * NHEADS + h;
    int s0 = st * 64;
    int tid = threadIdx.x;
    int sl = tid >> 2, g = tid & 3;
    int s = s0 + sl;
    const float* base = qkvb + ((size_t)(b * SEQ + s)) * 2304 + h * 64;

    // stage V tile (fp32) for transpose
    #pragma unroll
    for (int i = 0; i < 4; ++i) {
        float4 v = *(const float4*)(base + 1536 + g * 16 + i * 4);
        tv[sl][g * 16 + i * 4 + 0] = v.x;
        tv[sl][g * 16 + i * 4 + 1] = v.y;
        tv[sl][g * 16 + i * 4 + 2] = v.z;
        tv[sl][g * 16 + i * 4 + 3] = v.w;
    }

    // RoPE on q,k: this thread owns d = g*8..g*8+7 and partners +32
    float c[8], sn[8];
    #pragma unroll
    for (int i = 0; i < 8; ++i) {
        int fi = g * 8 + i;
        float ang = (float)s * exp2f(-(float)fi * 0.41524101186f);
        sincosf(ang, &sn[i], &c[i]);
    }
    float q1[8], q2[8], k1[8], k2[8];
    *(float4*)&q1[0] = *(const float4*)(base + g * 8);
    *(float4*)&q1[4] = *(const float4*)(base + g * 8 + 4);
    *(float4*)&q2[0] = *(const float4*)(base + g * 8 + 32);
    *(float4*)&q2[4] = *(const float4*)(base + g * 8 + 36);
    *(float4*)&k1[0] = *(const float4*)(base + 768 + g * 8);
    *(float4*)&k1[4] = *(const float4*)(base + 768 + g * 8 + 4);
    *(float4*)&k2[0] = *(const float4*)(base + 768 + g * 8 + 32);
    *(float4*)&k2[4] = *(const float4*)(base + 768 + g * 8 + 36);
    bf16x8 oq1, oq2, ok1, ok2;
    #pragma unroll
    for (int i = 0; i < 8; ++i) {
        oq1[i] = (short)f2bf(q1[i] * c[i] - q2[i] * sn[i]);
        oq2[i] = (short)f2bf(q2[i] * c[i] + q1[i] * sn[i]);
        ok1[i] = (short)f2bf(k1[i] * c[i] - k2[i] * sn[i]);
        ok2[i] = (short)f2bf(k2[i] * c[i] + k1[i] * sn[i]);
    }
    unsigned short* Qrow = Qb + ((size_t)bh * SEQ + s) * 64;
    unsigned short* Krow = Kb + ((size_t)bh * SEQ + s) * 64;
    *(bf16x8*)(Qrow + g * 8)      = oq1;
    *(bf16x8*)(Qrow + g * 8 + 32) = oq2;
    *(bf16x8*)(Krow + g * 8)      = ok1;
    *(bf16x8*)(Krow + g * 8 + 32) = ok2;

    __syncthreads();
    // V transpose out: thread -> (d row, 16-wide s group)
    int dr = tid >> 2, sg = tid & 3;
    bf16x8 ov0, ov1;
    #pragma unroll
    for (int i = 0; i < 8; ++i) {
        ov0[i] = (short)f2bf(tv[sg * 16 + i][dr]);
        ov1[i] = (short)f2bf(tv[sg * 16 + 8 + i][dr]);
    }
    unsigned short* vrow = Vt + ((size_t)bh * 64 + dr) * SEQ + s0 + sg * 16;
    *(bf16x8*)(vrow)     = ov0;
    *(bf16x8*)(vrow + 8) = ov1;
}

// ---------------- MFMA sliding-window attention ---------------------------
// block = (b, h, 64-query tile); 4 waves, wave w owns query rows w*16..w*16+15.
__global__ __launch_bounds__(256) void attn_mfma(const unsigned short* __restrict__ Qb,
                                                 const unsigned short* __restrict__ Kb,
                                                 const unsigned short* __restrict__ Vt,
                                                 const int* __restrict__ pmask,
                                                 unsigned short* __restrict__ ao) {
    __shared__ unsigned short Ks[KTA * 64];     // [192][64], 8 slots/row, slot ^= row&7
    __shared__ unsigned short Vs[64 * KTA];     // [64][192], 24 slots/row, low3 ^= d&7
    __shared__ unsigned short Ps[4][16 * KTA];  // per-wave P [16][192], swizzled like Vs
    __shared__ float pmsk[KTA];

    int bid = blockIdx.x;
    int qt = bid & 31;
    int h  = (bid >> 5) % NHEADS;
    int b  = bid / (32 * NHEADS);
    int bh = b * NHEADS + h;
    int q0 = qt * QTA;
    int kstart = q0 - 64;
    int tid = threadIdx.x;
    int wave = tid >> 6, lane = tid & 63;
    int fr = lane & 15, fq = lane >> 4;

    const unsigned short* Kg = Kb + ((size_t)bh * SEQ) * 64;
    const unsigned short* Vg = Vt + ((size_t)bh * 64) * SEQ;

    if (tid < KTA) {
        int k = kstart + tid;
        pmsk[tid] = (k >= 0 && k < SEQ) ? (1.0f - (float)pmask[b * SEQ + k]) * -1e9f
                                        : -1e9f;
    }

    bool interior = (qt != 0) && (qt != 31);
    if (interior) {
        #pragma unroll
        for (int r = 0; r < 6; ++r) {
            int c = r * 256 + tid;
            int row = c >> 3, slot = c & 7;
            int ss = slot ^ (row & 7);
            gload16(Kg + (size_t)(kstart + row) * 64 + ss * 8, (char*)Ks + c * 16);
        }
        #pragma unroll
        for (int r = 0; r < 6; ++r) {
            int c = r * 256 + tid;
            int d = c / 24, slot = c - d * 24;
            int ss = (slot & ~7) | ((slot & 7) ^ (d & 7));
            gload16(Vg + (size_t)d * SEQ + kstart + ss * 8, (char*)Vs + c * 16);
        }
    } else {
        #pragma unroll
        for (int r = 0; r < 6; ++r) {
            int c = r * 256 + tid;
            int row = c >> 3, slot = c & 7;
            int ss = slot ^ (row & 7);
            int sk = kstart + row;
            bf16x8 val = {0, 0, 0, 0, 0, 0, 0, 0};
            if (sk >= 0 && sk < SEQ)
                val = *(const bf16x8*)(Kg + (size_t)sk * 64 + ss * 8);
            *(bf16x8*)((char*)Ks + c * 16) = val;
        }
        #pragma unroll
        for (int r = 0; r < 6; ++r) {
            int c = r * 256 + tid;
            int d = c / 24, slot = c - d * 24;
            int ss = (slot & ~7) | ((slot & 7) ^ (d & 7));
            int start = kstart + ss * 8;
            bf16x8 val = {0, 0, 0, 0, 0, 0, 0, 0};
            if (start >= 0 && start + 8 <= SEQ)
                val = *(const bf16x8*)(Vg + (size_t)d * SEQ + start);
            *(bf16x8*)((char*)Vs + c * 16) = val;
        }
    }
    __syncthreads();

    // Q fragments direct from global
    const unsigned short* Qg = Qb + ((size_t)bh * SEQ + q0 + wave * 16 + fr) * 64 + fq * 8;
    bf16x8 qf0 = *(const bf16x8*)(Qg);
    bf16x8 qf1 = *(const bf16x8*)(Qg + 32);

    // QK^T: 12 n-tiles x 2 k-halves
    f32x4 sc[12];
    #pragma unroll
    for (int n = 0; n < 12; ++n) sc[n] = (f32x4){0.f, 0.f, 0.f, 0.f};
    #pragma unroll
    for (int n = 0; n < 12; ++n) {
        int row = n * 16 + fr;
        int base = row * 64;
        bf16x8 k0 = *(const bf16x8*)&Ks[base + ((fq)     ^ (row & 7)) * 8];
        bf16x8 k1 = *(const bf16x8*)&Ks[base + ((4 + fq) ^ (row & 7)) * 8];
        sc[n] = __builtin_amdgcn_mfma_f32_16x16x32_bf16(qf0, k0, sc[n], 0, 0, 0);
        sc[n] = __builtin_amdgcn_mfma_f32_16x16x32_bf16(qf1, k1, sc[n], 0, 0, 0);
    }

    // masks + row max
    int qrow_base = q0 + wave * 16 + fq * 4;
    float mj[4] = {-1e30f, -1e30f, -1e30f, -1e30f}, sj[4];
    #pragma unroll
    for (int n = 0; n < 12; ++n) {
        int k = kstart + n * 16 + fr;
        float pm = pmsk[n * 16 + fr];
        #pragma unroll
        for (int j = 0; j < 4; ++j) {
            int diff = qrow_base + j - k;
            float s = sc[n][j] * 0.125f + pm;
            if (diff > 64 || diff < -64) s = -1e30f;
            sc[n][j] = s;
            mj[j] = fmaxf(mj[j], s);
        }
    }
    #pragma unroll
    for (int j = 0; j < 4; ++j) {
        #pragma unroll
        for (int mk = 1; mk < 16; mk <<= 1)
            mj[j] = fmaxf(mj[j], __shfl_xor(mj[j], mk, 16));
        sj[j] = 0.f;
    }
    #pragma unroll
    for (int n = 0; n < 12; ++n)
        #pragma unroll
        for (int j = 0; j < 4; ++j) {
            float e = expf(sc[n][j] - mj[j]);
            sc[n][j] = e;
            sj[j] += e;
        }
    #pragma unroll
    for (int j = 0; j < 4; ++j)
        #pragma unroll
        for (int mk = 1; mk < 16; mk <<= 1)
            sj[j] += __shfl_xor(sj[j], mk, 16);

    // P -> per-wave LDS (bf16, swizzled)
    unsigned short* Pw = Ps[wave];
    #pragma unroll
    for (int n = 0; n < 12; ++n) {
        int slot = n * 2 + (fr >> 3);
        #pragma unroll
        for (int j = 0; j < 4; ++j) {
            int row = fq * 4 + j;
            int ss = (slot & ~7) | ((slot & 7) ^ (row & 7));
            Pw[row * KTA + ss * 8 + (fr & 7)] = f2bf(sc[n][j]);
        }
    }

    // PV: O[16][64] = P(16x192) @ V(192x64)
    f32x4 oacc[4];
    #pragma unroll
    for (int n = 0; n < 4; ++n) oacc[n] = (f32x4){0.f, 0.f, 0.f, 0.f};
    #pragma unroll
    for (int kt = 0; kt < 6; ++kt) {
        int slot = kt * 4 + fq;
        int ssp = (slot & ~7) | ((slot & 7) ^ (fr & 7));
        bf16x8 pa = *(const bf16x8*)&Pw[fr * KTA + ssp * 8];
        #pragma unroll
        for (int n = 0; n < 4; ++n) {
            int d = n * 16 + fr;
            int ssv = (slot & ~7) | ((slot & 7) ^ (d & 7));
            bf16x8 vf = *(const bf16x8*)&Vs[d * KTA + ssv * 8];
            oacc[n] = __builtin_amdgcn_mfma_f32_16x16x32_bf16(pa, vf, oacc[n], 0, 0, 0);
        }
    }

    // epilogue
    unsigned short* aob = ao + ((size_t)(b * SEQ + qrow_base)) * HID + h * 64;
    float rs[4];
    #pragma unroll
    for (int j = 0; j < 4; ++j) rs[j] = 1.0f / sj[j];
    #pragma unroll
    for (int n = 0; n < 4; ++n)
        #pragma unroll
        for (int j = 0; j < 4; ++j)
            aob[(size_t)j * HID + n * 16 + fr] = f2bf(oacc[n][j] * rs[j]);
}

// ---------------- gated GELU on concat wi output: row-wise ----------------
__global__ __launch_bounds__(256) void gelumul_kernel(const float* __restrict__ mm,
                                                      unsigned short* __restrict__ o) {
    int row = blockIdx.x, t = threadIdx.x;
    const float4* ar = (const float4*)(mm + (size_t)row * 2304);
    unsigned short* orow = o + (size_t)row * INTER;
    #pragma unroll
    for (int rpt = 0; rpt < 2; ++rpt) {
        int i = t + rpt * 256;
        if (i < 288) {
            float4 va = ar[i], vb = ar[288 + i];
            float r[4] = {va.x, va.y, va.z, va.w};
            float m[4] = {vb.x, vb.y, vb.z, vb.w};
            ushort4 ov;
            unsigned short p[4];
            #pragma unroll
            for (int j = 0; j < 4; ++j) {
                float xa = r[j];
                float tn = tanhf(0.7978845608028654f * (xa + 0.044715f * xa * xa * xa));
                p[j] = f2bf(0.5f * xa * (1.f + tn) * m[j]);
            }
            ov.x = p[0]; ov.y = p[1]; ov.z = p[2]; ov.w = p[3];
            *(ushort4*)(orow + i * 4) = ov;
        }
    }
}

extern "C" void kernel_launch(void* const* d_in, const int* in_sizes, int n_in,
                              void* d_out, int out_size, void* d_ws, size_t ws_size,
                              hipStream_t stream) {
    const float* x       = (const float*)d_in[0];
    const int*   pmask   = (const int*)d_in[1];
    const float* wqkv    = (const float*)d_in[2];
    const float* wo_attn = (const float*)d_in[3];
    const float* wi0     = (const float*)d_in[4];
    const float* wi1     = (const float*)d_in[5];
    const float* wo_mlp  = (const float*)d_in[6];
    const float* g_attn  = (const float*)d_in[7];
    const float* g_mlp   = (const float*)d_in[8];
    float* out = (float*)d_out;

    char* w = (char*)d_ws;
    unsigned short* hbf   = (unsigned short*)w;                 // 6291456 B
    unsigned short* aobf  = (unsigned short*)(w + 6291456);     // 6291456 B
    unsigned short* mgate = (unsigned short*)w;                 // alias hbf+aobf (9.4MB<12.6MB)
    float* qkvb = (float*)(w + 12582912);                       // 37748736 B
    float* mm   = qkvb;                                         // alias (qkv dead after prep)
    unsigned short* Qb = (unsigned short*)(w + 50331648);       // 6291456 B
    unsigned short* Kb = (unsigned short*)(w + 56623104);       // 6291456 B
    unsigned short* Vt = (unsigned short*)(w + 62914560);       // 6291456 B
    char* wts = w + 69206016;
    unsigned short* wqkvT = (unsigned short*)(wts);                       // [2304][768]
    unsigned short* woaT  = (unsigned short*)(wts + 3538944);             // [768][768]
    unsigned short* wiT   = (unsigned short*)(wts + 3538944 + 1179648);   // [2304][768] concat
    unsigned short* womT  = (unsigned short*)(wts + 3538944 + 1179648 + 3538944); // [768][1152]

    // 0. weight transpose+convert
    wt_kernel<<<dim3(2304 / 32, 768 / 32), 256, 0, stream>>>(wqkv, wqkvT, 768, 2304);
    wt_kernel<<<dim3(768 / 32, 768 / 32), 256, 0, stream>>>(wo_attn, woaT, 768, 768);
    wt_kernel<<<dim3(1152 / 32, 768 / 32), 256, 0, stream>>>(wi0, wiT, 768, 1152);
    wt_kernel<<<dim3(1152 / 32, 768 / 32), 256, 0, stream>>>(wi1, wiT + (size_t)1152 * 768, 768, 1152);
    wt_kernel<<<dim3(768 / 32, 1152 / 32), 256, 0, stream>>>(wo_mlp, womT, 1152, 768);

    // 1. h = rmsnorm(x, g_attn)
    rmsnorm_kernel<<<ROWS, 256, 0, stream>>>(x, g_attn, hbf);
    // 2. qkv = h @ wqkv
    mfma_gemm<<<dim3(2304 / 128, ROWS / 128), 256, 0, stream>>>(hbf, wqkvT, nullptr, qkvb, 2304, 768);
    // 3. RoPE + bf16 convert + V transpose
    qkvprep<<<NB * NHEADS * (SEQ / 64), 256, 0, stream>>>(qkvb, Qb, Kb, Vt);
    // 4. MFMA sliding-window attention
    attn_mfma<<<NB * NHEADS * (SEQ / QTA), 256, 0, stream>>>(Qb, Kb, Vt, pmask, aobf);
    // 5. x1 = x + ao @ wo_attn  -> d_out
    mfma_gemm<<<dim3(768 / 128, ROWS / 128), 256, 0, stream>>>(aobf, woaT, x, out, 768, 768);
    // 6. h = rmsnorm(x1, g_mlp)
    rmsnorm_kernel<<<ROWS, 256, 0, stream>>>(out, g_mlp, hbf);
    // 7. mm = h @ [wi0|wi1]
    mfma_gemm<<<dim3(2304 / 128, ROWS / 128), 256, 0, stream>>>(hbf, wiT, nullptr, mm, 2304, 768);
    // 8. mgate = gelu(mm[:, :1152]) * mm[:, 1152:]
    gelumul_kernel<<<ROWS, 256, 0, stream>>>(mm, mgate);
    // 9. out = x1 + mgate @ wo_mlp
    mfma_gemm<<<dim3(768 / 128, ROWS / 128), 256, 0, stream>>>(mgate, womT, out, out, 768, 1152);
}

// Round 4
// 170.640 us; speedup vs baseline: 4.3932x; 1.2543x over previous
//
#include <hip/hip_runtime.h>
#include <hip/hip_bf16.h>

#define HID 768
#define NHEADS 12
#define HD 64
#define INTER 1152
#define SEQ 2048
#define NB 2
#define ROWS (NB * SEQ)   // 4096
#define QTA 64            // queries per attention block
#define KTA 192           // key panel: QTA + 2*64

typedef __attribute__((ext_vector_type(8))) short bf16x8;
typedef __attribute__((ext_vector_type(4))) float f32x4;

__device__ __forceinline__ float bf2f(unsigned short u) {
    union { unsigned int i; float f; } c; c.i = ((unsigned int)u) << 16; return c.f;
}
__device__ __forceinline__ unsigned short f2bf(float f) {
    union { float f; unsigned int i; } c; c.f = f;
    unsigned int b = c.i;
    b += 0x7FFFu + ((b >> 16) & 1u);   // round-to-nearest-even
    return (unsigned short)(b >> 16);
}
__device__ __forceinline__ void gload16(const void* g, void* l) {
    __builtin_amdgcn_global_load_lds((const __attribute__((address_space(1))) unsigned int*)g,
                                     (__attribute__((address_space(3))) unsigned int*)l,
                                     16, 0, 0);
}

// ---------------- RMSNorm: one block per row (768 cols), bf16 out --------
__global__ __launch_bounds__(256) void rmsnorm_kernel(const float* __restrict__ x,
                                                      const float* __restrict__ g,
                                                      unsigned short* __restrict__ out) {
    int row = blockIdx.x;
    const float* xr = x + (size_t)row * HID;
    unsigned short* orow = out + (size_t)row * HID;
    int tid = threadIdx.x;
    float v0 = xr[tid], v1 = xr[tid + 256], v2 = xr[tid + 512];
    float s = v0 * v0 + v1 * v1 + v2 * v2;
    #pragma unroll
    for (int m = 32; m >= 1; m >>= 1) s += __shfl_xor(s, m, 64);
    __shared__ float red[4];
    if ((tid & 63) == 0) red[tid >> 6] = s;
    __syncthreads();
    float tot = red[0] + red[1] + red[2] + red[3];
    float inv = rsqrtf(tot * (1.0f / HID) + 1e-5f);
    orow[tid]       = f2bf(v0 * inv * g[tid]);
    orow[tid + 256] = f2bf(v1 * inv * g[tid + 256]);
    orow[tid + 512] = f2bf(v2 * inv * g[tid + 512]);
}

// ------------- weight transpose+convert: W[K][N] fp32 -> Wt[N][K] bf16 ---
__global__ __launch_bounds__(256) void wt_kernel(const float* __restrict__ W,
                                                 unsigned short* __restrict__ Wt,
                                                 int K, int N) {
    __shared__ float t[32][33];
    int bx = blockIdx.x * 32;   // n tile
    int by = blockIdx.y * 32;   // k tile
    int tx = threadIdx.x & 31, ty = threadIdx.x >> 5;
    #pragma unroll
    for (int i = 0; i < 4; ++i)
        t[ty + i * 8][tx] = W[(size_t)(by + ty + i * 8) * N + bx + tx];
    __syncthreads();
    #pragma unroll
    for (int i = 0; i < 4; ++i)
        Wt[(size_t)(bx + ty + i * 8) * K + by + tx] = f2bf(t[tx][ty + i * 8]);
}

// ---------------- bf16 MFMA GEMM: C[M,N] = A[M,K] @ Bt[N,K]^T (+resid) ---
// 128x128 tile, BK=32, 4 waves (2x2). LDS [row][32], slot ^= (row>>1)&3.
__global__ __launch_bounds__(256) void mfma_gemm(const unsigned short* __restrict__ A,
                                                 const unsigned short* __restrict__ Bt,
                                                 const float* __restrict__ resid,
                                                 float* __restrict__ C,
                                                 int N, int K) {
    __shared__ unsigned short As[128 * 32];
    __shared__ unsigned short Bs[128 * 32];
    int tid = threadIdx.x;
    int wave = tid >> 6, lane = tid & 63;
    int row0 = blockIdx.y * 128, col0 = blockIdx.x * 128;
    int wr = wave >> 1, wc = wave & 1;
    int fr = lane & 15, fq = lane >> 4;

    f32x4 acc[4][4];
    #pragma unroll
    for (int m = 0; m < 4; ++m)
        #pragma unroll
        for (int n = 0; n < 4; ++n)
            acc[m][n] = (f32x4){0.f, 0.f, 0.f, 0.f};

    const size_t strideA = (size_t)K * 2;
    const char* Ab = (const char*)A;
    const char* Bb = (const char*)Bt;

    for (int k0 = 0; k0 < K; k0 += 32) {
        #pragma unroll
        for (int c = 0; c < 2; ++c) {
            int L = c * 4096 + wave * 1024 + lane * 16;
            int r = L >> 6;
            int ss = ((L >> 4) & 3) ^ ((r >> 1) & 3);
            gload16(Ab + (size_t)(row0 + r) * strideA + (size_t)k0 * 2 + ss * 16,
                    (char*)As + c * 4096 + wave * 1024);
            gload16(Bb + (size_t)(col0 + r) * strideA + (size_t)k0 * 2 + ss * 16,
                    (char*)Bs + c * 4096 + wave * 1024);
        }
        __syncthreads();
        bf16x8 af[4], bfr[4];
        #pragma unroll
        for (int m = 0; m < 4; ++m) {
            int row = wr * 64 + m * 16 + fr;
            int ss = fq ^ ((row >> 1) & 3);
            af[m] = *(const bf16x8*)&As[row * 32 + ss * 8];
        }
        #pragma unroll
        for (int n = 0; n < 4; ++n) {
            int row = wc * 64 + n * 16 + fr;
            int ss = fq ^ ((row >> 1) & 3);
            bfr[n] = *(const bf16x8*)&Bs[row * 32 + ss * 8];
        }
        #pragma unroll
        for (int m = 0; m < 4; ++m)
            #pragma unroll
            for (int n = 0; n < 4; ++n)
                acc[m][n] = __builtin_amdgcn_mfma_f32_16x16x32_bf16(af[m], bfr[n], acc[m][n], 0, 0, 0);
        __syncthreads();
    }

    #pragma unroll
    for (int m = 0; m < 4; ++m) {
        #pragma unroll
        for (int j = 0; j < 4; ++j) {
            size_t r = (size_t)(row0 + wr * 64 + m * 16 + fq * 4 + j);
            #pragma unroll
            for (int n = 0; n < 4; ++n) {
                size_t idx = r * N + (col0 + wc * 64 + n * 16 + fr);
                float v = acc[m][n][j];
                if (resid) v += resid[idx];
                C[idx] = v;
            }
        }
    }
}

// ------- small-N bf16 MFMA GEMM: 64x64 tile, BK=64, 4 waves (2x2) --------
// For skinny GEMMs (N=768): grid 12x64=768 blocks -> 3 blocks/CU.
// LDS [row][64], 8 slots/row, slot ^= row&7 (conflict-free, attn-verified).
__global__ __launch_bounds__(256) void mfma_gemm64(const unsigned short* __restrict__ A,
                                                   const unsigned short* __restrict__ Bt,
                                                   const float* __restrict__ resid,
                                                   float* __restrict__ C,
                                                   int N, int K) {
    __shared__ unsigned short As[64 * 64];
    __shared__ unsigned short Bs[64 * 64];
    int tid = threadIdx.x;
    int wave = tid >> 6, lane = tid & 63;
    int row0 = blockIdx.y * 64, col0 = blockIdx.x * 64;
    int wr = wave >> 1, wc = wave & 1;
    int fr = lane & 15, fq = lane >> 4;

    f32x4 acc[2][2];
    #pragma unroll
    for (int m = 0; m < 2; ++m)
        #pragma unroll
        for (int n = 0; n < 2; ++n)
            acc[m][n] = (f32x4){0.f, 0.f, 0.f, 0.f};

    const size_t strideA = (size_t)K * 2;
    const char* Ab = (const char*)A;
    const char* Bb = (const char*)Bt;

    for (int k0 = 0; k0 < K; k0 += 64) {
        #pragma unroll
        for (int r = 0; r < 2; ++r) {
            int L = r * 4096 + tid * 16;       // byte offset in tile
            int row = L >> 7;
            int ss = ((L >> 4) & 7) ^ (row & 7);
            gload16(Ab + (size_t)(row0 + row) * strideA + (size_t)k0 * 2 + ss * 16,
                    (char*)As + L);
            gload16(Bb + (size_t)(col0 + row) * strideA + (size_t)k0 * 2 + ss * 16,
                    (char*)Bs + L);
        }
        __syncthreads();
        bf16x8 af[2][2], bff[2][2];
        #pragma unroll
        for (int m = 0; m < 2; ++m)
            #pragma unroll
            for (int kk = 0; kk < 2; ++kk) {
                int rowa = wr * 32 + m * 16 + fr;
                int ssa = ((kk * 4 + fq) ^ (rowa & 7));
                af[m][kk] = *(const bf16x8*)&As[rowa * 64 + ssa * 8];
                int rowb = wc * 32 + m * 16 + fr;
                int ssb = ((kk * 4 + fq) ^ (rowb & 7));
                bff[m][kk] = *(const bf16x8*)&Bs[rowb * 64 + ssb * 8];
            }
        #pragma unroll
        for (int m = 0; m < 2; ++m)
            #pragma unroll
            for (int n = 0; n < 2; ++n) {
                acc[m][n] = __builtin_amdgcn_mfma_f32_16x16x32_bf16(af[m][0], bff[n][0], acc[m][n], 0, 0, 0);
                acc[m][n] = __builtin_amdgcn_mfma_f32_16x16x32_bf16(af[m][1], bff[n][1], acc[m][n], 0, 0, 0);
            }
        __syncthreads();
    }

    #pragma unroll
    for (int m = 0; m < 2; ++m) {
        #pragma unroll
        for (int j = 0; j < 4; ++j) {
            size_t r = (size_t)(row0 + wr * 32 + m * 16 + fq * 4 + j);
            #pragma unroll
            for (int n = 0; n < 2; ++n) {
                size_t idx = r * N + (col0 + wc * 32 + n * 16 + fr);
                float v = acc[m][n][j];
                if (resid) v += resid[idx];
                C[idx] = v;
            }
        }
    }
}

// -------- qkvprep: fp32 qkv -> RoPE'd bf16 Q,K [B,H,S,64] + V^T [B,H,64,S]
__global__ __launch_bounds__(256) void qkvprep(const float* __restrict__ qkvb,
                                               unsigned short* __restrict__ Qb,
                                               unsigned short* __restrict__ Kb,
                                               unsigned short* __restrict__ Vt) {
    __shared__ float tv[64][65];
    int bid = blockIdx.x;
    int st = bid & 31;
    int h  = (bid >> 5) % NHEADS;
    int b  = bid / (32 * NHEADS);
    int bh = b * NHEADS + h;
    int s0 = st * 64;
    int tid = threadIdx.x;
    int sl = tid >> 2, g = tid & 3;
    int s = s0 + sl;
    const float* base = qkvb + ((size_t)(b * SEQ + s)) * 2304 + h * 64;

    #pragma unroll
    for (int i = 0; i < 4; ++i) {
        float4 v = *(const float4*)(base + 1536 + g * 16 + i * 4);
        tv[sl][g * 16 + i * 4 + 0] = v.x;
        tv[sl][g * 16 + i * 4 + 1] = v.y;
        tv[sl][g * 16 + i * 4 + 2] = v.z;
        tv[sl][g * 16 + i * 4 + 3] = v.w;
    }

    float c[8], sn[8];
    #pragma unroll
    for (int i = 0; i < 8; ++i) {
        int fi = g * 8 + i;
        float ang = (float)s * exp2f(-(float)fi * 0.41524101186f);
        sincosf(ang, &sn[i], &c[i]);
    }
    float q1[8], q2[8], k1[8], k2[8];
    *(float4*)&q1[0] = *(const float4*)(base + g * 8);
    *(float4*)&q1[4] = *(const float4*)(base + g * 8 + 4);
    *(float4*)&q2[0] = *(const float4*)(base + g * 8 + 32);
    *(float4*)&q2[4] = *(const float4*)(base + g * 8 + 36);
    *(float4*)&k1[0] = *(const float4*)(base + 768 + g * 8);
    *(float4*)&k1[4] = *(const float4*)(base + 768 + g * 8 + 4);
    *(float4*)&k2[0] = *(const float4*)(base + 768 + g * 8 + 32);
    *(float4*)&k2[4] = *(const float4*)(base + 768 + g * 8 + 36);
    bf16x8 oq1, oq2, ok1, ok2;
    #pragma unroll
    for (int i = 0; i < 8; ++i) {
        oq1[i] = (short)f2bf(q1[i] * c[i] - q2[i] * sn[i]);
        oq2[i] = (short)f2bf(q2[i] * c[i] + q1[i] * sn[i]);
        ok1[i] = (short)f2bf(k1[i] * c[i] - k2[i] * sn[i]);
        ok2[i] = (short)f2bf(k2[i] * c[i] + k1[i] * sn[i]);
    }
    unsigned short* Qrow = Qb + ((size_t)bh * SEQ + s) * 64;
    unsigned short* Krow = Kb + ((size_t)bh * SEQ + s) * 64;
    *(bf16x8*)(Qrow + g * 8)      = oq1;
    *(bf16x8*)(Qrow + g * 8 + 32) = oq2;
    *(bf16x8*)(Krow + g * 8)      = ok1;
    *(bf16x8*)(Krow + g * 8 + 32) = ok2;

    __syncthreads();
    int dr = tid >> 2, sg = tid & 3;
    bf16x8 ov0, ov1;
    #pragma unroll
    for (int i = 0; i < 8; ++i) {
        ov0[i] = (short)f2bf(tv[sg * 16 + i][dr]);
        ov1[i] = (short)f2bf(tv[sg * 16 + 8 + i][dr]);
    }
    unsigned short* vrow = Vt + ((size_t)bh * 64 + dr) * SEQ + s0 + sg * 16;
    *(bf16x8*)(vrow)     = ov0;
    *(bf16x8*)(vrow + 8) = ov1;
}

// ---------------- MFMA sliding-window attention ---------------------------
__global__ __launch_bounds__(256) void attn_mfma(const unsigned short* __restrict__ Qb,
                                                 const unsigned short* __restrict__ Kb,
                                                 const unsigned short* __restrict__ Vt,
                                                 const int* __restrict__ pmask,
                                                 unsigned short* __restrict__ ao) {
    __shared__ unsigned short Ks[KTA * 64];
    __shared__ unsigned short Vs[64 * KTA];
    __shared__ unsigned short Ps[4][16 * KTA];
    __shared__ float pmsk[KTA];

    int bid = blockIdx.x;
    int qt = bid & 31;
    int h  = (bid >> 5) % NHEADS;
    int b  = bid / (32 * NHEADS);
    int bh = b * NHEADS + h;
    int q0 = qt * QTA;
    int kstart = q0 - 64;
    int tid = threadIdx.x;
    int wave = tid >> 6, lane = tid & 63;
    int fr = lane & 15, fq = lane >> 4;

    const unsigned short* Kg = Kb + ((size_t)bh * SEQ) * 64;
    const unsigned short* Vg = Vt + ((size_t)bh * 64) * SEQ;

    if (tid < KTA) {
        int k = kstart + tid;
        pmsk[tid] = (k >= 0 && k < SEQ) ? (1.0f - (float)pmask[b * SEQ + k]) * -1e9f
                                        : -1e9f;
    }

    bool interior = (qt != 0) && (qt != 31);
    if (interior) {
        #pragma unroll
        for (int r = 0; r < 6; ++r) {
            int c = r * 256 + tid;
            int row = c >> 3, slot = c & 7;
            int ss = slot ^ (row & 7);
            gload16(Kg + (size_t)(kstart + row) * 64 + ss * 8, (char*)Ks + c * 16);
        }
        #pragma unroll
        for (int r = 0; r < 6; ++r) {
            int c = r * 256 + tid;
            int d = c / 24, slot = c - d * 24;
            int ss = (slot & ~7) | ((slot & 7) ^ (d & 7));
            gload16(Vg + (size_t)d * SEQ + kstart + ss * 8, (char*)Vs + c * 16);
        }
    } else {
        #pragma unroll
        for (int r = 0; r < 6; ++r) {
            int c = r * 256 + tid;
            int row = c >> 3, slot = c & 7;
            int ss = slot ^ (row & 7);
            int sk = kstart + row;
            bf16x8 val = {0, 0, 0, 0, 0, 0, 0, 0};
            if (sk >= 0 && sk < SEQ)
                val = *(const bf16x8*)(Kg + (size_t)sk * 64 + ss * 8);
            *(bf16x8*)((char*)Ks + c * 16) = val;
        }
        #pragma unroll
        for (int r = 0; r < 6; ++r) {
            int c = r * 256 + tid;
            int d = c / 24, slot = c - d * 24;
            int ss = (slot & ~7) | ((slot & 7) ^ (d & 7));
            int start = kstart + ss * 8;
            bf16x8 val = {0, 0, 0, 0, 0, 0, 0, 0};
            if (start >= 0 && start + 8 <= SEQ)
                val = *(const bf16x8*)(Vg + (size_t)d * SEQ + start);
            *(bf16x8*)((char*)Vs + c * 16) = val;
        }
    }
    __syncthreads();

    const unsigned short* Qg = Qb + ((size_t)bh * SEQ + q0 + wave * 16 + fr) * 64 + fq * 8;
    bf16x8 qf0 = *(const bf16x8*)(Qg);
    bf16x8 qf1 = *(const bf16x8*)(Qg + 32);

    f32x4 sc[12];
    #pragma unroll
    for (int n = 0; n < 12; ++n) sc[n] = (f32x4){0.f, 0.f, 0.f, 0.f};
    #pragma unroll
    for (int n = 0; n < 12; ++n) {
        int row = n * 16 + fr;
        int base = row * 64;
        bf16x8 k0 = *(const bf16x8*)&Ks[base + ((fq)     ^ (row & 7)) * 8];
        bf16x8 k1 = *(const bf16x8*)&Ks[base + ((4 + fq) ^ (row & 7)) * 8];
        sc[n] = __builtin_amdgcn_mfma_f32_16x16x32_bf16(qf0, k0, sc[n], 0, 0, 0);
        sc[n] = __builtin_amdgcn_mfma_f32_16x16x32_bf16(qf1, k1, sc[n], 0, 0, 0);
    }

    int qrow_base = q0 + wave * 16 + fq * 4;
    float mj[4] = {-1e30f, -1e30f, -1e30f, -1e30f}, sj[4];
    #pragma unroll
    for (int n = 0; n < 12; ++n) {
        int k = kstart + n * 16 + fr;
        float pm = pmsk[n * 16 + fr];
        #pragma unroll
        for (int j = 0; j < 4; ++j) {
            int diff = qrow_base + j - k;
            float s = sc[n][j] * 0.125f + pm;
            if (diff > 64 || diff < -64) s = -1e30f;
            sc[n][j] = s;
            mj[j] = fmaxf(mj[j], s);
        }
    }
    #pragma unroll
    for (int j = 0; j < 4; ++j) {
        #pragma unroll
        for (int mk = 1; mk < 16; mk <<= 1)
            mj[j] = fmaxf(mj[j], __shfl_xor(mj[j], mk, 16));
        sj[j] = 0.f;
    }
    #pragma unroll
    for (int n = 0; n < 12; ++n)
        #pragma unroll
        for (int j = 0; j < 4; ++j) {
            float e = expf(sc[n][j] - mj[j]);
            sc[n][j] = e;
            sj[j] += e;
        }
    #pragma unroll
    for (int j = 0; j < 4; ++j)
        #pragma unroll
        for (int mk = 1; mk < 16; mk <<= 1)
            sj[j] += __shfl_xor(sj[j], mk, 16);

    unsigned short* Pw = Ps[wave];
    #pragma unroll
    for (int n = 0; n < 12; ++n) {
        int slot = n * 2 + (fr >> 3);
        #pragma unroll
        for (int j = 0; j < 4; ++j) {
            int row = fq * 4 + j;
            int ss = (slot & ~7) | ((slot & 7) ^ (row & 7));
            Pw[row * KTA + ss * 8 + (fr & 7)] = f2bf(sc[n][j]);
        }
    }

    f32x4 oacc[4];
    #pragma unroll
    for (int n = 0; n < 4; ++n) oacc[n] = (f32x4){0.f, 0.f, 0.f, 0.f};
    #pragma unroll
    for (int kt = 0; kt < 6; ++kt) {
        int slot = kt * 4 + fq;
        int ssp = (slot & ~7) | ((slot & 7) ^ (fr & 7));
        bf16x8 pa = *(const bf16x8*)&Pw[fr * KTA + ssp * 8];
        #pragma unroll
        for (int n = 0; n < 4; ++n) {
            int d = n * 16 + fr;
            int ssv = (slot & ~7) | ((slot & 7) ^ (d & 7));
            bf16x8 vf = *(const bf16x8*)&Vs[d * KTA + ssv * 8];
            oacc[n] = __builtin_amdgcn_mfma_f32_16x16x32_bf16(pa, vf, oacc[n], 0, 0, 0);
        }
    }

    unsigned short* aob = ao + ((size_t)(b * SEQ + qrow_base)) * HID + h * 64;
    float rs[4];
    #pragma unroll
    for (int j = 0; j < 4; ++j) rs[j] = 1.0f / sj[j];
    #pragma unroll
    for (int n = 0; n < 4; ++n)
        #pragma unroll
        for (int j = 0; j < 4; ++j)
            aob[(size_t)j * HID + n * 16 + fr] = f2bf(oacc[n][j] * rs[j]);
}

// ---------------- gated GELU on concat wi output: row-wise ----------------
__global__ __launch_bounds__(256) void gelumul_kernel(const float* __restrict__ mm,
                                                      unsigned short* __restrict__ o) {
    int row = blockIdx.x, t = threadIdx.x;
    const float4* ar = (const float4*)(mm + (size_t)row * 2304);
    unsigned short* orow = o + (size_t)row * INTER;
    #pragma unroll
    for (int rpt = 0; rpt < 2; ++rpt) {
        int i = t + rpt * 256;
        if (i < 288) {
            float4 va = ar[i], vb = ar[288 + i];
            float r[4] = {va.x, va.y, va.z, va.w};
            float m[4] = {vb.x, vb.y, vb.z, vb.w};
            ushort4 ov;
            unsigned short p[4];
            #pragma unroll
            for (int j = 0; j < 4; ++j) {
                float xa = r[j];
                float tn = tanhf(0.7978845608028654f * (xa + 0.044715f * xa * xa * xa));
                p[j] = f2bf(0.5f * xa * (1.f + tn) * m[j]);
            }
            ov.x = p[0]; ov.y = p[1]; ov.z = p[2]; ov.w = p[3];
            *(ushort4*)(orow + i * 4) = ov;
        }
    }
}

extern "C" void kernel_launch(void* const* d_in, const int* in_sizes, int n_in,
                              void* d_out, int out_size, void* d_ws, size_t ws_size,
                              hipStream_t stream) {
    const float* x       = (const float*)d_in[0];
    const int*   pmask   = (const int*)d_in[1];
    const float* wqkv    = (const float*)d_in[2];
    const float* wo_attn = (const float*)d_in[3];
    const float* wi0     = (const float*)d_in[4];
    const float* wi1     = (const float*)d_in[5];
    const float* wo_mlp  = (const float*)d_in[6];
    const float* g_attn  = (const float*)d_in[7];
    const float* g_mlp   = (const float*)d_in[8];
    float* out = (float*)d_out;

    char* w = (char*)d_ws;
    unsigned short* hbf   = (unsigned short*)w;                 // 6291456 B
    unsigned short* aobf  = (unsigned short*)(w + 6291456);     // 6291456 B
    unsigned short* mgate = (unsigned short*)w;                 // alias hbf+aobf
    float* qkvb = (float*)(w + 12582912);                       // 37748736 B
    float* mm   = qkvb;                                         // alias (qkv dead after prep)
    unsigned short* Qb = (unsigned short*)(w + 50331648);       // 6291456 B
    unsigned short* Kb = (unsigned short*)(w + 56623104);       // 6291456 B
    unsigned short* Vt = (unsigned short*)(w + 62914560);       // 6291456 B
    char* wts = w + 69206016;
    unsigned short* wqkvT = (unsigned short*)(wts);                       // [2304][768]
    unsigned short* woaT  = (unsigned short*)(wts + 3538944);             // [768][768]
    unsigned short* wiT   = (unsigned short*)(wts + 3538944 + 1179648);   // [2304][768]
    unsigned short* womT  = (unsigned short*)(wts + 3538944 + 1179648 + 3538944); // [768][1152]

    // 0. weight transpose+convert
    wt_kernel<<<dim3(2304 / 32, 768 / 32), 256, 0, stream>>>(wqkv, wqkvT, 768, 2304);
    wt_kernel<<<dim3(768 / 32, 768 / 32), 256, 0, stream>>>(wo_attn, woaT, 768, 768);
    wt_kernel<<<dim3(1152 / 32, 768 / 32), 256, 0, stream>>>(wi0, wiT, 768, 1152);
    wt_kernel<<<dim3(1152 / 32, 768 / 32), 256, 0, stream>>>(wi1, wiT + (size_t)1152 * 768, 768, 1152);
    wt_kernel<<<dim3(768 / 32, 1152 / 32), 256, 0, stream>>>(wo_mlp, womT, 1152, 768);

    // 1. h = rmsnorm(x, g_attn)
    rmsnorm_kernel<<<ROWS, 256, 0, stream>>>(x, g_attn, hbf);
    // 2. qkv = h @ wqkv
    mfma_gemm<<<dim3(2304 / 128, ROWS / 128), 256, 0, stream>>>(hbf, wqkvT, nullptr, qkvb, 2304, 768);
    // 3. RoPE + bf16 convert + V transpose
    qkvprep<<<NB * NHEADS * (SEQ / 64), 256, 0, stream>>>(qkvb, Qb, Kb, Vt);
    // 4. MFMA sliding-window attention
    attn_mfma<<<NB * NHEADS * (SEQ / QTA), 256, 0, stream>>>(Qb, Kb, Vt, pmask, aobf);
    // 5. x1 = x + ao @ wo_attn  -> d_out  (skinny: 64x64 tiles, 768 blocks)
    mfma_gemm64<<<dim3(768 / 64, ROWS / 64), 256, 0, stream>>>(aobf, woaT, x, out, 768, 768);
    // 6. h = rmsnorm(x1, g_mlp)
    rmsnorm_kernel<<<ROWS, 256, 0, stream>>>(out, g_mlp, hbf);
    // 7. mm = h @ [wi0|wi1]
    mfma_gemm<<<dim3(2304 / 128, ROWS / 128), 256, 0, stream>>>(hbf, wiT, nullptr, mm, 2304, 768);
    // 8. mgate = gelu(mm[:, :1152]) * mm[:, 1152:]
    gelumul_kernel<<<ROWS, 256, 0, stream>>>(mm, mgate);
    // 9. out = x1 + mgate @ wo_mlp  (skinny: 64x64 tiles, 768 blocks)
    mfma_gemm64<<<dim3(768 / 64, ROWS / 64), 256, 0, stream>>>(mgate, womT, out, out, 768, 1152);
}

// Round 5
// 149.635 us; speedup vs baseline: 5.0099x; 1.1404x over previous
//
#include <hip/hip_runtime.h>
#include <hip/hip_bf16.h>

#define HID 768
#define NHEADS 12
#define HD 64
#define INTER 1152
#define SEQ 2048
#define NB 2
#define ROWS (NB * SEQ)   // 4096
#define QTA 64            // queries per attention block
#define KTA 192           // key panel: QTA + 2*64

typedef __attribute__((ext_vector_type(8))) short bf16x8;
typedef __attribute__((ext_vector_type(4))) float f32x4;

__device__ __forceinline__ float bf2f(unsigned short u) {
    union { unsigned int i; float f; } c; c.i = ((unsigned int)u) << 16; return c.f;
}
__device__ __forceinline__ unsigned short f2bf(float f) {
    union { float f; unsigned int i; } c; c.f = f;
    unsigned int b = c.i;
    b += 0x7FFFu + ((b >> 16) & 1u);   // round-to-nearest-even
    return (unsigned short)(b >> 16);
}
__device__ __forceinline__ void gload16(const void* g, void* l) {
    __builtin_amdgcn_global_load_lds((const __attribute__((address_space(1))) unsigned int*)g,
                                     (__attribute__((address_space(3))) unsigned int*)l,
                                     16, 0, 0);
}

// ---------------- RMSNorm: one block per row (768 cols), bf16 out --------
__global__ __launch_bounds__(256) void rmsnorm_kernel(const float* __restrict__ x,
                                                      const float* __restrict__ g,
                                                      unsigned short* __restrict__ out) {
    int row = blockIdx.x;
    const float* xr = x + (size_t)row * HID;
    unsigned short* orow = out + (size_t)row * HID;
    int tid = threadIdx.x;
    float v0 = xr[tid], v1 = xr[tid + 256], v2 = xr[tid + 512];
    float s = v0 * v0 + v1 * v1 + v2 * v2;
    #pragma unroll
    for (int m = 32; m >= 1; m >>= 1) s += __shfl_xor(s, m, 64);
    __shared__ float red[4];
    if ((tid & 63) == 0) red[tid >> 6] = s;
    __syncthreads();
    float tot = red[0] + red[1] + red[2] + red[3];
    float inv = rsqrtf(tot * (1.0f / HID) + 1e-5f);
    orow[tid]       = f2bf(v0 * inv * g[tid]);
    orow[tid + 256] = f2bf(v1 * inv * g[tid + 256]);
    orow[tid + 512] = f2bf(v2 * inv * g[tid + 512]);
}

// ------------- weight transpose+convert: W[K][N] fp32 -> Wt[N][K] bf16 ---
__global__ __launch_bounds__(256) void wt_kernel(const float* __restrict__ W,
                                                 unsigned short* __restrict__ Wt,
                                                 int K, int N) {
    __shared__ float t[32][33];
    int bx = blockIdx.x * 32;   // n tile
    int by = blockIdx.y * 32;   // k tile
    int tx = threadIdx.x & 31, ty = threadIdx.x >> 5;
    #pragma unroll
    for (int i = 0; i < 4; ++i)
        t[ty + i * 8][tx] = W[(size_t)(by + ty + i * 8) * N + bx + tx];
    __syncthreads();
    #pragma unroll
    for (int i = 0; i < 4; ++i)
        Wt[(size_t)(bx + ty + i * 8) * K + by + tx] = f2bf(t[tx][ty + i * 8]);
}

// ---------------- RoPE cos/sin table: tab[s][fi] = (cos, sin) ------------
__global__ __launch_bounds__(256) void ropetab_kernel(float2* __restrict__ tab) {
    int idx = blockIdx.x * 256 + threadIdx.x;   // 65536 = 2048*32
    int s = idx >> 5, fi = idx & 31;
    float ang = (float)s * exp2f(-(float)fi * 0.41524101186f);
    float sn, cs;
    sincosf(ang, &sn, &cs);
    tab[idx] = make_float2(cs, sn);
}

// ------- small-N bf16 MFMA GEMM: 64x64 tile, BK=64, 4 waves (2x2) --------
// LDS [row][64], 8 slots/row, slot ^= row&7 (conflict-free, attn-verified).
__global__ __launch_bounds__(256) void mfma_gemm64(const unsigned short* __restrict__ A,
                                                   const unsigned short* __restrict__ Bt,
                                                   const float* __restrict__ resid,
                                                   float* __restrict__ C,
                                                   int N, int K) {
    __shared__ unsigned short As[64 * 64];
    __shared__ unsigned short Bs[64 * 64];
    int tid = threadIdx.x;
    int wave = tid >> 6, lane = tid & 63;
    int row0 = blockIdx.y * 64, col0 = blockIdx.x * 64;
    int wr = wave >> 1, wc = wave & 1;
    int fr = lane & 15, fq = lane >> 4;

    f32x4 acc[2][2];
    #pragma unroll
    for (int m = 0; m < 2; ++m)
        #pragma unroll
        for (int n = 0; n < 2; ++n)
            acc[m][n] = (f32x4){0.f, 0.f, 0.f, 0.f};

    const size_t strideA = (size_t)K * 2;
    const char* Ab = (const char*)A;
    const char* Bb = (const char*)Bt;

    for (int k0 = 0; k0 < K; k0 += 64) {
        #pragma unroll
        for (int r = 0; r < 2; ++r) {
            int L = r * 4096 + tid * 16;       // byte offset in tile
            int row = L >> 7;
            int ss = ((L >> 4) & 7) ^ (row & 7);
            gload16(Ab + (size_t)(row0 + row) * strideA + (size_t)k0 * 2 + ss * 16,
                    (char*)As + L);
            gload16(Bb + (size_t)(col0 + row) * strideA + (size_t)k0 * 2 + ss * 16,
                    (char*)Bs + L);
        }
        __syncthreads();
        bf16x8 af[2][2], bff[2][2];
        #pragma unroll
        for (int m = 0; m < 2; ++m)
            #pragma unroll
            for (int kk = 0; kk < 2; ++kk) {
                int rowa = wr * 32 + m * 16 + fr;
                int ssa = ((kk * 4 + fq) ^ (rowa & 7));
                af[m][kk] = *(const bf16x8*)&As[rowa * 64 + ssa * 8];
                int rowb = wc * 32 + m * 16 + fr;
                int ssb = ((kk * 4 + fq) ^ (rowb & 7));
                bff[m][kk] = *(const bf16x8*)&Bs[rowb * 64 + ssb * 8];
            }
        #pragma unroll
        for (int m = 0; m < 2; ++m)
            #pragma unroll
            for (int n = 0; n < 2; ++n) {
                acc[m][n] = __builtin_amdgcn_mfma_f32_16x16x32_bf16(af[m][0], bff[n][0], acc[m][n], 0, 0, 0);
                acc[m][n] = __builtin_amdgcn_mfma_f32_16x16x32_bf16(af[m][1], bff[n][1], acc[m][n], 0, 0, 0);
            }
        __syncthreads();
    }

    #pragma unroll
    for (int m = 0; m < 2; ++m) {
        #pragma unroll
        for (int j = 0; j < 4; ++j) {
            size_t r = (size_t)(row0 + wr * 32 + m * 16 + fq * 4 + j);
            #pragma unroll
            for (int n = 0; n < 2; ++n) {
                size_t idx = r * N + (col0 + wc * 32 + n * 16 + fr);
                float v = acc[m][n][j];
                if (resid) v += resid[idx];
                C[idx] = v;
            }
        }
    }
}

// ------- fused qkv GEMM: 64x64 tile, wave = 16 rows x 64 cols ------------
// Epilogue: type 0/1 -> RoPE in-register -> Qb/Kb [bh][s][64] bf16;
//           type 2   -> LDS transpose -> Vt [bh][64][s] bf16.
__global__ __launch_bounds__(256) void gemm_qkv(const unsigned short* __restrict__ A,
                                                const unsigned short* __restrict__ Bt,
                                                const float2* __restrict__ rtab,
                                                unsigned short* __restrict__ Qb,
                                                unsigned short* __restrict__ Kb,
                                                unsigned short* __restrict__ Vt) {
    __shared__ unsigned short smem[2 * 64 * 64];
    unsigned short* As = smem;
    unsigned short* Bs = smem + 64 * 64;
    int tid = threadIdx.x;
    int wave = tid >> 6, lane = tid & 63;
    int fr = lane & 15, fq = lane >> 4;
    int col0 = blockIdx.x * 64, row0 = blockIdx.y * 64;
    int type = col0 / 768;              // 0=q, 1=k, 2=v (tiles align to heads)
    int h = (col0 % 768) >> 6;
    int b = row0 >> 11;
    int s0 = row0 & 2047;
    int bh = b * NHEADS + h;

    f32x4 acc[4];
    #pragma unroll
    for (int n = 0; n < 4; ++n) acc[n] = (f32x4){0.f, 0.f, 0.f, 0.f};

    const size_t strideA = (size_t)768 * 2;
    const char* Ab = (const char*)A;
    const char* Bb = (const char*)Bt;

    for (int k0 = 0; k0 < 768; k0 += 64) {
        #pragma unroll
        for (int r = 0; r < 2; ++r) {
            int L = r * 4096 + tid * 16;
            int row = L >> 7;
            int ss = ((L >> 4) & 7) ^ (row & 7);
            gload16(Ab + (size_t)(row0 + row) * strideA + (size_t)k0 * 2 + ss * 16,
                    (char*)As + L);
            gload16(Bb + (size_t)(col0 + row) * strideA + (size_t)k0 * 2 + ss * 16,
                    (char*)Bs + L);
        }
        __syncthreads();
        bf16x8 af[2];
        int rowa = wave * 16 + fr;
        #pragma unroll
        for (int kk = 0; kk < 2; ++kk)
            af[kk] = *(const bf16x8*)&As[rowa * 64 + ((kk * 4 + fq) ^ (rowa & 7)) * 8];
        #pragma unroll
        for (int n = 0; n < 4; ++n) {
            int rowb = n * 16 + fr;
            bf16x8 b0 = *(const bf16x8*)&Bs[rowb * 64 + ((fq) ^ (rowb & 7)) * 8];
            bf16x8 b1 = *(const bf16x8*)&Bs[rowb * 64 + ((4 + fq) ^ (rowb & 7)) * 8];
            acc[n] = __builtin_amdgcn_mfma_f32_16x16x32_bf16(af[0], b0, acc[n], 0, 0, 0);
            acc[n] = __builtin_amdgcn_mfma_f32_16x16x32_bf16(af[1], b1, acc[n], 0, 0, 0);
        }
        __syncthreads();
    }

    if (type < 2) {
        // RoPE: partner col d^32 = acc[n^2] (same lane)
        unsigned short* P = (type == 0 ? Qb : Kb) + ((size_t)bh * SEQ) * 64;
        #pragma unroll
        for (int n = 0; n < 4; ++n) {
            int d = n * 16 + fr;
            int fi = d & 31;
            #pragma unroll
            for (int j = 0; j < 4; ++j) {
                int s = s0 + wave * 16 + fq * 4 + j;
                float2 cs = rtab[s * 32 + fi];
                float val = acc[n][j], par = acc[n ^ 2][j];
                float o = (d < 32) ? val * cs.x - par * cs.y
                                   : val * cs.x + par * cs.y;
                P[(size_t)s * 64 + d] = f2bf(o);
            }
        }
    } else {
        // V: LDS transpose (row stride 72 to spread banks) -> coalesced store
        unsigned short* vt = smem;   // 64*72*2 = 9216 B <= 16384 B
        #pragma unroll
        for (int n = 0; n < 4; ++n) {
            int d = n * 16 + fr;
            #pragma unroll
            for (int j = 0; j < 4; ++j)
                vt[d * 72 + wave * 16 + fq * 4 + j] = f2bf(acc[n][j]);
        }
        __syncthreads();
        int d = tid >> 2, sg = tid & 3;
        bf16x8 o0 = *(const bf16x8*)&vt[d * 72 + sg * 16];
        bf16x8 o1 = *(const bf16x8*)&vt[d * 72 + sg * 16 + 8];
        unsigned short* vrow = Vt + ((size_t)bh * 64 + d) * SEQ + s0 + sg * 16;
        *(bf16x8*)(vrow)     = o0;
        *(bf16x8*)(vrow + 8) = o1;
    }
}

// ------- fused FFN-in GEMM: gelu(h@wi0) * (h@wi1) -> bf16 mgate ----------
// 64x64 tile, wave = 16 rows x 64 cols, dual B-panels.
__global__ __launch_bounds__(256) void gemm_ffn(const unsigned short* __restrict__ A,
                                                const unsigned short* __restrict__ B0t,
                                                const unsigned short* __restrict__ B1t,
                                                unsigned short* __restrict__ O) {
    __shared__ unsigned short As[64 * 64];
    __shared__ unsigned short Bs0[64 * 64];
    __shared__ unsigned short Bs1[64 * 64];
    int tid = threadIdx.x;
    int wave = tid >> 6, lane = tid & 63;
    int fr = lane & 15, fq = lane >> 4;
    int col0 = blockIdx.x * 64, row0 = blockIdx.y * 64;

    f32x4 acc0[4], acc1[4];
    #pragma unroll
    for (int n = 0; n < 4; ++n) {
        acc0[n] = (f32x4){0.f, 0.f, 0.f, 0.f};
        acc1[n] = (f32x4){0.f, 0.f, 0.f, 0.f};
    }

    const size_t strideA = (size_t)768 * 2;
    const char* Ab  = (const char*)A;
    const char* B0b = (const char*)B0t;
    const char* B1b = (const char*)B1t;

    for (int k0 = 0; k0 < 768; k0 += 64) {
        #pragma unroll
        for (int r = 0; r < 2; ++r) {
            int L = r * 4096 + tid * 16;
            int row = L >> 7;
            int ss = ((L >> 4) & 7) ^ (row & 7);
            size_t goffA = (size_t)(row0 + row) * strideA + (size_t)k0 * 2 + ss * 16;
            size_t goffB = (size_t)(col0 + row) * strideA + (size_t)k0 * 2 + ss * 16;
            gload16(Ab + goffA,  (char*)As  + L);
            gload16(B0b + goffB, (char*)Bs0 + L);
            gload16(B1b + goffB, (char*)Bs1 + L);
        }
        __syncthreads();
        bf16x8 af[2];
        int rowa = wave * 16 + fr;
        #pragma unroll
        for (int kk = 0; kk < 2; ++kk)
            af[kk] = *(const bf16x8*)&As[rowa * 64 + ((kk * 4 + fq) ^ (rowa & 7)) * 8];
        #pragma unroll
        for (int n = 0; n < 4; ++n) {
            int rowb = n * 16 + fr;
            int sl0 = ((fq) ^ (rowb & 7)) * 8, sl1 = ((4 + fq) ^ (rowb & 7)) * 8;
            bf16x8 b00 = *(const bf16x8*)&Bs0[rowb * 64 + sl0];
            bf16x8 b01 = *(const bf16x8*)&Bs0[rowb * 64 + sl1];
            bf16x8 b10 = *(const bf16x8*)&Bs1[rowb * 64 + sl0];
            bf16x8 b11 = *(const bf16x8*)&Bs1[rowb * 64 + sl1];
            acc0[n] = __builtin_amdgcn_mfma_f32_16x16x32_bf16(af[0], b00, acc0[n], 0, 0, 0);
            acc0[n] = __builtin_amdgcn_mfma_f32_16x16x32_bf16(af[1], b01, acc0[n], 0, 0, 0);
            acc1[n] = __builtin_amdgcn_mfma_f32_16x16x32_bf16(af[0], b10, acc1[n], 0, 0, 0);
            acc1[n] = __builtin_amdgcn_mfma_f32_16x16x32_bf16(af[1], b11, acc1[n], 0, 0, 0);
        }
        __syncthreads();
    }

    #pragma unroll
    for (int n = 0; n < 4; ++n) {
        #pragma unroll
        for (int j = 0; j < 4; ++j) {
            int r = row0 + wave * 16 + fq * 4 + j;
            float xa = acc0[n][j];
            float tn = tanhf(0.7978845608028654f * (xa + 0.044715f * xa * xa * xa));
            float gv = 0.5f * xa * (1.f + tn) * acc1[n][j];
            O[(size_t)r * INTER + col0 + n * 16 + fr] = f2bf(gv);
        }
    }
}

// ---------------- MFMA sliding-window attention ---------------------------
__global__ __launch_bounds__(256) void attn_mfma(const unsigned short* __restrict__ Qb,
                                                 const unsigned short* __restrict__ Kb,
                                                 const unsigned short* __restrict__ Vt,
                                                 const int* __restrict__ pmask,
                                                 unsigned short* __restrict__ ao) {
    __shared__ unsigned short Ks[KTA * 64];
    __shared__ unsigned short Vs[64 * KTA];
    __shared__ unsigned short Ps[4][16 * KTA];
    __shared__ float pmsk[KTA];

    int bid = blockIdx.x;
    int qt = bid & 31;
    int h  = (bid >> 5) % NHEADS;
    int b  = bid / (32 * NHEADS);
    int bh = b * NHEADS + h;
    int q0 = qt * QTA;
    int kstart = q0 - 64;
    int tid = threadIdx.x;
    int wave = tid >> 6, lane = tid & 63;
    int fr = lane & 15, fq = lane >> 4;

    const unsigned short* Kg = Kb + ((size_t)bh * SEQ) * 64;
    const unsigned short* Vg = Vt + ((size_t)bh * 64) * SEQ;

    if (tid < KTA) {
        int k = kstart + tid;
        pmsk[tid] = (k >= 0 && k < SEQ) ? (1.0f - (float)pmask[b * SEQ + k]) * -1e9f
                                        : -1e9f;
    }

    bool interior = (qt != 0) && (qt != 31);
    if (interior) {
        #pragma unroll
        for (int r = 0; r < 6; ++r) {
            int c = r * 256 + tid;
            int row = c >> 3, slot = c & 7;
            int ss = slot ^ (row & 7);
            gload16(Kg + (size_t)(kstart + row) * 64 + ss * 8, (char*)Ks + c * 16);
        }
        #pragma unroll
        for (int r = 0; r < 6; ++r) {
            int c = r * 256 + tid;
            int d = c / 24, slot = c - d * 24;
            int ss = (slot & ~7) | ((slot & 7) ^ (d & 7));
            gload16(Vg + (size_t)d * SEQ + kstart + ss * 8, (char*)Vs + c * 16);
        }
    } else {
        #pragma unroll
        for (int r = 0; r < 6; ++r) {
            int c = r * 256 + tid;
            int row = c >> 3, slot = c & 7;
            int ss = slot ^ (row & 7);
            int sk = kstart + row;
            bf16x8 val = {0, 0, 0, 0, 0, 0, 0, 0};
            if (sk >= 0 && sk < SEQ)
                val = *(const bf16x8*)(Kg + (size_t)sk * 64 + ss * 8);
            *(bf16x8*)((char*)Ks + c * 16) = val;
        }
        #pragma unroll
        for (int r = 0; r < 6; ++r) {
            int c = r * 256 + tid;
            int d = c / 24, slot = c - d * 24;
            int ss = (slot & ~7) | ((slot & 7) ^ (d & 7));
            int start = kstart + ss * 8;
            bf16x8 val = {0, 0, 0, 0, 0, 0, 0, 0};
            if (start >= 0 && start + 8 <= SEQ)
                val = *(const bf16x8*)(Vg + (size_t)d * SEQ + start);
            *(bf16x8*)((char*)Vs + c * 16) = val;
        }
    }
    __syncthreads();

    const unsigned short* Qg = Qb + ((size_t)bh * SEQ + q0 + wave * 16 + fr) * 64 + fq * 8;
    bf16x8 qf0 = *(const bf16x8*)(Qg);
    bf16x8 qf1 = *(const bf16x8*)(Qg + 32);

    f32x4 sc[12];
    #pragma unroll
    for (int n = 0; n < 12; ++n) sc[n] = (f32x4){0.f, 0.f, 0.f, 0.f};
    #pragma unroll
    for (int n = 0; n < 12; ++n) {
        int row = n * 16 + fr;
        int base = row * 64;
        bf16x8 k0 = *(const bf16x8*)&Ks[base + ((fq)     ^ (row & 7)) * 8];
        bf16x8 k1 = *(const bf16x8*)&Ks[base + ((4 + fq) ^ (row & 7)) * 8];
        sc[n] = __builtin_amdgcn_mfma_f32_16x16x32_bf16(qf0, k0, sc[n], 0, 0, 0);
        sc[n] = __builtin_amdgcn_mfma_f32_16x16x32_bf16(qf1, k1, sc[n], 0, 0, 0);
    }

    int qrow_base = q0 + wave * 16 + fq * 4;
    float mj[4] = {-1e30f, -1e30f, -1e30f, -1e30f}, sj[4];
    #pragma unroll
    for (int n = 0; n < 12; ++n) {
        int k = kstart + n * 16 + fr;
        float pm = pmsk[n * 16 + fr];
        #pragma unroll
        for (int j = 0; j < 4; ++j) {
            int diff = qrow_base + j - k;
            float s = sc[n][j] * 0.125f + pm;
            if (diff > 64 || diff < -64) s = -1e30f;
            sc[n][j] = s;
            mj[j] = fmaxf(mj[j], s);
        }
    }
    #pragma unroll
    for (int j = 0; j < 4; ++j) {
        #pragma unroll
        for (int mk = 1; mk < 16; mk <<= 1)
            mj[j] = fmaxf(mj[j], __shfl_xor(mj[j], mk, 16));
        sj[j] = 0.f;
    }
    #pragma unroll
    for (int n = 0; n < 12; ++n)
        #pragma unroll
        for (int j = 0; j < 4; ++j) {
            float e = expf(sc[n][j] - mj[j]);
            sc[n][j] = e;
            sj[j] += e;
        }
    #pragma unroll
    for (int j = 0; j < 4; ++j)
        #pragma unroll
        for (int mk = 1; mk < 16; mk <<= 1)
            sj[j] += __shfl_xor(sj[j], mk, 16);

    unsigned short* Pw = Ps[wave];
    #pragma unroll
    for (int n = 0; n < 12; ++n) {
        int slot = n * 2 + (fr >> 3);
        #pragma unroll
        for (int j = 0; j < 4; ++j) {
            int row = fq * 4 + j;
            int ss = (slot & ~7) | ((slot & 7) ^ (row & 7));
            Pw[row * KTA + ss * 8 + (fr & 7)] = f2bf(sc[n][j]);
        }
    }

    f32x4 oacc[4];
    #pragma unroll
    for (int n = 0; n < 4; ++n) oacc[n] = (f32x4){0.f, 0.f, 0.f, 0.f};
    #pragma unroll
    for (int kt = 0; kt < 6; ++kt) {
        int slot = kt * 4 + fq;
        int ssp = (slot & ~7) | ((slot & 7) ^ (fr & 7));
        bf16x8 pa = *(const bf16x8*)&Pw[fr * KTA + ssp * 8];
        #pragma unroll
        for (int n = 0; n < 4; ++n) {
            int d = n * 16 + fr;
            int ssv = (slot & ~7) | ((slot & 7) ^ (d & 7));
            bf16x8 vf = *(const bf16x8*)&Vs[d * KTA + ssv * 8];
            oacc[n] = __builtin_amdgcn_mfma_f32_16x16x32_bf16(pa, vf, oacc[n], 0, 0, 0);
        }
    }

    unsigned short* aob = ao + ((size_t)(b * SEQ + qrow_base)) * HID + h * 64;
    float rs[4];
    #pragma unroll
    for (int j = 0; j < 4; ++j) rs[j] = 1.0f / sj[j];
    #pragma unroll
    for (int n = 0; n < 4; ++n)
        #pragma unroll
        for (int j = 0; j < 4; ++j)
            aob[(size_t)j * HID + n * 16 + fr] = f2bf(oacc[n][j] * rs[j]);
}

extern "C" void kernel_launch(void* const* d_in, const int* in_sizes, int n_in,
                              void* d_out, int out_size, void* d_ws, size_t ws_size,
                              hipStream_t stream) {
    const float* x       = (const float*)d_in[0];
    const int*   pmask   = (const int*)d_in[1];
    const float* wqkv    = (const float*)d_in[2];
    const float* wo_attn = (const float*)d_in[3];
    const float* wi0     = (const float*)d_in[4];
    const float* wi1     = (const float*)d_in[5];
    const float* wo_mlp  = (const float*)d_in[6];
    const float* g_attn  = (const float*)d_in[7];
    const float* g_mlp   = (const float*)d_in[8];
    float* out = (float*)d_out;

    char* w = (char*)d_ws;
    unsigned short* hbf   = (unsigned short*)(w);              // 6291456 B
    unsigned short* aobf  = (unsigned short*)(w + 6291456);    // 6291456 B
    unsigned short* Qb    = (unsigned short*)(w + 12582912);   // 6291456 B
    unsigned short* Kb    = (unsigned short*)(w + 18874368);   // 6291456 B
    unsigned short* Vt    = (unsigned short*)(w + 25165824);   // 6291456 B
    unsigned short* mgate = (unsigned short*)(w + 31457280);   // 9437184 B
    float2*         rtab  = (float2*)(w + 40894464);           // 524288 B
    unsigned short* wqkvT = (unsigned short*)(w + 41418752);   // [2304][768]
    unsigned short* woaT  = (unsigned short*)(w + 44957696);   // [768][768]
    unsigned short* wi0T  = (unsigned short*)(w + 46137344);   // [1152][768]
    unsigned short* wi1T  = (unsigned short*)(w + 47906816);   // [1152][768]
    unsigned short* womT  = (unsigned short*)(w + 49676288);   // [768][1152]

    // 0. weight transpose+convert + rope table
    wt_kernel<<<dim3(2304 / 32, 768 / 32), 256, 0, stream>>>(wqkv, wqkvT, 768, 2304);
    wt_kernel<<<dim3(768 / 32, 768 / 32), 256, 0, stream>>>(wo_attn, woaT, 768, 768);
    wt_kernel<<<dim3(1152 / 32, 768 / 32), 256, 0, stream>>>(wi0, wi0T, 768, 1152);
    wt_kernel<<<dim3(1152 / 32, 768 / 32), 256, 0, stream>>>(wi1, wi1T, 768, 1152);
    wt_kernel<<<dim3(768 / 32, 1152 / 32), 256, 0, stream>>>(wo_mlp, womT, 1152, 768);
    ropetab_kernel<<<256, 256, 0, stream>>>(rtab);

    // 1. h = rmsnorm(x, g_attn)
    rmsnorm_kernel<<<ROWS, 256, 0, stream>>>(x, g_attn, hbf);
    // 2. fused qkv GEMM + RoPE + layout -> Qb, Kb, Vt
    gemm_qkv<<<dim3(2304 / 64, ROWS / 64), 256, 0, stream>>>(hbf, wqkvT, rtab, Qb, Kb, Vt);
    // 3. MFMA sliding-window attention
    attn_mfma<<<NB * NHEADS * (SEQ / QTA), 256, 0, stream>>>(Qb, Kb, Vt, pmask, aobf);
    // 4. x1 = x + ao @ wo_attn  -> d_out
    mfma_gemm64<<<dim3(768 / 64, ROWS / 64), 256, 0, stream>>>(aobf, woaT, x, out, 768, 768);
    // 5. h = rmsnorm(x1, g_mlp)
    rmsnorm_kernel<<<ROWS, 256, 0, stream>>>(out, g_mlp, hbf);
    // 6. mgate = gelu(h@wi0) * (h@wi1)  (fused, bf16 out)
    gemm_ffn<<<dim3(INTER / 64, ROWS / 64), 256, 0, stream>>>(hbf, wi0T, wi1T, mgate);
    // 7. out = x1 + mgate @ wo_mlp
    mfma_gemm64<<<dim3(768 / 64, ROWS / 64), 256, 0, stream>>>(mgate, womT, out, out, 768, 1152);
}

// Round 6
// 128.330 us; speedup vs baseline: 5.8416x; 1.1660x over previous
//
#include <hip/hip_runtime.h>
#include <hip/hip_bf16.h>

#define HID 768
#define NHEADS 12
#define HD 64
#define INTER 1152
#define SEQ 2048
#define NB 2
#define ROWS (NB * SEQ)   // 4096
#define QTA 64            // queries per attention block
#define KTA 192           // key panel: QTA + 2*64

typedef __attribute__((ext_vector_type(8))) short bf16x8;
typedef __attribute__((ext_vector_type(4))) float f32x4;

__device__ __forceinline__ float bf2f(unsigned short u) {
    union { unsigned int i; float f; } c; c.i = ((unsigned int)u) << 16; return c.f;
}
__device__ __forceinline__ unsigned short f2bf(float f) {
    union { float f; unsigned int i; } c; c.f = f;
    unsigned int b = c.i;
    b += 0x7FFFu + ((b >> 16) & 1u);   // round-to-nearest-even
    return (unsigned short)(b >> 16);
}
__device__ __forceinline__ void gload16(const void* g, void* l) {
    __builtin_amdgcn_global_load_lds((const __attribute__((address_space(1))) unsigned int*)g,
                                     (__attribute__((address_space(3))) unsigned int*)l,
                                     16, 0, 0);
}

// ---------------- RMSNorm: one block per row (768 cols), bf16 out --------
__global__ __launch_bounds__(256) void rmsnorm_kernel(const float* __restrict__ x,
                                                      const float* __restrict__ g,
                                                      unsigned short* __restrict__ out) {
    int row = blockIdx.x;
    const float* xr = x + (size_t)row * HID;
    unsigned short* orow = out + (size_t)row * HID;
    int tid = threadIdx.x;
    float v0 = xr[tid], v1 = xr[tid + 256], v2 = xr[tid + 512];
    float s = v0 * v0 + v1 * v1 + v2 * v2;
    #pragma unroll
    for (int m = 32; m >= 1; m >>= 1) s += __shfl_xor(s, m, 64);
    __shared__ float red[4];
    if ((tid & 63) == 0) red[tid >> 6] = s;
    __syncthreads();
    float tot = red[0] + red[1] + red[2] + red[3];
    float inv = rsqrtf(tot * (1.0f / HID) + 1e-5f);
    orow[tid]       = f2bf(v0 * inv * g[tid]);
    orow[tid + 256] = f2bf(v1 * inv * g[tid + 256]);
    orow[tid + 512] = f2bf(v2 * inv * g[tid + 512]);
}

// ---- merged prep: 5 weight transposes (fp32 [K][N] -> bf16 [N][K]) + rope
__device__ __forceinline__ void wt_tile(const float* __restrict__ W,
                                        unsigned short* __restrict__ Wt,
                                        int K, int N, int bx, int by,
                                        float (*t)[33]) {
    int tx = threadIdx.x & 31, ty = threadIdx.x >> 5;
    #pragma unroll
    for (int i = 0; i < 4; ++i)
        t[ty + i * 8][tx] = W[(size_t)(by * 32 + ty + i * 8) * N + bx * 32 + tx];
    __syncthreads();
    #pragma unroll
    for (int i = 0; i < 4; ++i)
        Wt[(size_t)(bx * 32 + ty + i * 8) * K + by * 32 + tx] = f2bf(t[tx][ty + i * 8]);
}

__global__ __launch_bounds__(256) void prep_kernel(const float* __restrict__ wqkv,
                                                   const float* __restrict__ woa,
                                                   const float* __restrict__ wi0,
                                                   const float* __restrict__ wi1,
                                                   const float* __restrict__ wom,
                                                   unsigned short* __restrict__ wqkvT,
                                                   unsigned short* __restrict__ woaT,
                                                   unsigned short* __restrict__ wi0T,
                                                   unsigned short* __restrict__ wi1T,
                                                   unsigned short* __restrict__ womT,
                                                   float2* __restrict__ rtab) {
    __shared__ float t[32][33];
    int id = blockIdx.x;
    if (id < 1728)       wt_tile(wqkv, wqkvT, 768, 2304, id % 72, id / 72, t);
    else if (id < 2304)  { id -= 1728; wt_tile(woa, woaT, 768, 768, id % 24, id / 24, t); }
    else if (id < 3168)  { id -= 2304; wt_tile(wi0, wi0T, 768, 1152, id % 36, id / 36, t); }
    else if (id < 4032)  { id -= 3168; wt_tile(wi1, wi1T, 768, 1152, id % 36, id / 36, t); }
    else if (id < 4896)  { id -= 4032; wt_tile(wom, womT, 1152, 768, id % 24, id / 24, t); }
    else {
        int idx = (id - 4896) * 256 + threadIdx.x;   // 65536 = 2048*32
        int s = idx >> 5, fi = idx & 31;
        float ang = (float)s * exp2f(-(float)fi * 0.41524101186f);
        float sn, cs;
        sincosf(ang, &sn, &cs);
        rtab[idx] = make_float2(cs, sn);
    }
}

// ------- small-N bf16 MFMA GEMM: 64x64 tile, BK=64, 4 waves (2x2) --------
// 1D grid + bijective XCD swizzle (nwg % 8 == 0 guaranteed by caller).
__global__ __launch_bounds__(256) void mfma_gemm64(const unsigned short* __restrict__ A,
                                                   const unsigned short* __restrict__ Bt,
                                                   const float* __restrict__ resid,
                                                   float* __restrict__ C,
                                                   int N, int K, int nbx) {
    __shared__ unsigned short As[64 * 64];
    __shared__ unsigned short Bs[64 * 64];
    int nwg = gridDim.x;
    int bid = blockIdx.x;
    int id2 = (bid & 7) * (nwg >> 3) + (bid >> 3);
    int row0 = (id2 / nbx) * 64, col0 = (id2 % nbx) * 64;
    int tid = threadIdx.x;
    int wave = tid >> 6, lane = tid & 63;
    int wr = wave >> 1, wc = wave & 1;
    int fr = lane & 15, fq = lane >> 4;

    f32x4 acc[2][2];
    #pragma unroll
    for (int m = 0; m < 2; ++m)
        #pragma unroll
        for (int n = 0; n < 2; ++n)
            acc[m][n] = (f32x4){0.f, 0.f, 0.f, 0.f};

    const size_t strideA = (size_t)K * 2;
    const char* Ab = (const char*)A;
    const char* Bb = (const char*)Bt;

    for (int k0 = 0; k0 < K; k0 += 64) {
        #pragma unroll
        for (int r = 0; r < 2; ++r) {
            int L = r * 4096 + tid * 16;
            int row = L >> 7;
            int ss = ((L >> 4) & 7) ^ (row & 7);
            gload16(Ab + (size_t)(row0 + row) * strideA + (size_t)k0 * 2 + ss * 16,
                    (char*)As + L);
            gload16(Bb + (size_t)(col0 + row) * strideA + (size_t)k0 * 2 + ss * 16,
                    (char*)Bs + L);
        }
        __syncthreads();
        bf16x8 af[2][2], bff[2][2];
        #pragma unroll
        for (int m = 0; m < 2; ++m)
            #pragma unroll
            for (int kk = 0; kk < 2; ++kk) {
                int rowa = wr * 32 + m * 16 + fr;
                af[m][kk] = *(const bf16x8*)&As[rowa * 64 + ((kk * 4 + fq) ^ (rowa & 7)) * 8];
                int rowb = wc * 32 + m * 16 + fr;
                bff[m][kk] = *(const bf16x8*)&Bs[rowb * 64 + ((kk * 4 + fq) ^ (rowb & 7)) * 8];
            }
        #pragma unroll
        for (int m = 0; m < 2; ++m)
            #pragma unroll
            for (int n = 0; n < 2; ++n) {
                acc[m][n] = __builtin_amdgcn_mfma_f32_16x16x32_bf16(af[m][0], bff[n][0], acc[m][n], 0, 0, 0);
                acc[m][n] = __builtin_amdgcn_mfma_f32_16x16x32_bf16(af[m][1], bff[n][1], acc[m][n], 0, 0, 0);
            }
        __syncthreads();
    }

    #pragma unroll
    for (int m = 0; m < 2; ++m) {
        #pragma unroll
        for (int j = 0; j < 4; ++j) {
            size_t r = (size_t)(row0 + wr * 32 + m * 16 + fq * 4 + j);
            #pragma unroll
            for (int n = 0; n < 2; ++n) {
                size_t idx = r * N + (col0 + wc * 32 + n * 16 + fr);
                float v = acc[m][n][j];
                if (resid) v += resid[idx];
                C[idx] = v;
            }
        }
    }
}

// ------ fused qkv GEMM: 128x64 tile, wave = 32 rows x 64 cols, BK=64 -----
// 16 MFMA : 12 ds_read per wave-iter. Epilogue: RoPE (q,k) / V-transpose.
__global__ __launch_bounds__(256) void gemm_qkv128(const unsigned short* __restrict__ A,
                                                   const unsigned short* __restrict__ Bt,
                                                   const float2* __restrict__ rtab,
                                                   unsigned short* __restrict__ Qb,
                                                   unsigned short* __restrict__ Kb,
                                                   unsigned short* __restrict__ Vt) {
    __shared__ unsigned short As[128 * 64];   // 16 KB
    __shared__ unsigned short Bs[64 * 64];    // 8 KB
    int bid = blockIdx.x;                      // 1152 blocks
    int id2 = (bid & 7) * 144 + (bid >> 3);
    int col0 = (id2 % 36) * 64, row0 = (id2 / 36) * 128;
    int tid = threadIdx.x;
    int wave = tid >> 6, lane = tid & 63;
    int fr = lane & 15, fq = lane >> 4;
    int type = col0 / 768;              // 0=q, 1=k, 2=v (64-tiles align to heads)
    int h = (col0 % 768) >> 6;
    int b = row0 >> 11;
    int s0 = row0 & 2047;
    int bh = b * NHEADS + h;

    f32x4 acc[2][4];
    #pragma unroll
    for (int m = 0; m < 2; ++m)
        #pragma unroll
        for (int n = 0; n < 4; ++n)
            acc[m][n] = (f32x4){0.f, 0.f, 0.f, 0.f};

    const size_t strideA = (size_t)768 * 2;
    const char* Ab = (const char*)A;
    const char* Bb = (const char*)Bt;

    for (int k0 = 0; k0 < 768; k0 += 64) {
        #pragma unroll
        for (int r = 0; r < 4; ++r) {
            int L = r * 4096 + tid * 16;
            int row = L >> 7;
            int ss = ((L >> 4) & 7) ^ (row & 7);
            gload16(Ab + (size_t)(row0 + row) * strideA + (size_t)k0 * 2 + ss * 16,
                    (char*)As + L);
        }
        #pragma unroll
        for (int r = 0; r < 2; ++r) {
            int L = r * 4096 + tid * 16;
            int row = L >> 7;
            int ss = ((L >> 4) & 7) ^ (row & 7);
            gload16(Bb + (size_t)(col0 + row) * strideA + (size_t)k0 * 2 + ss * 16,
                    (char*)Bs + L);
        }
        __syncthreads();
        #pragma unroll
        for (int kk = 0; kk < 2; ++kk) {
            bf16x8 af[2], bf[4];
            #pragma unroll
            for (int m = 0; m < 2; ++m) {
                int rowa = wave * 32 + m * 16 + fr;
                af[m] = *(const bf16x8*)&As[rowa * 64 + ((kk * 4 + fq) ^ (rowa & 7)) * 8];
            }
            #pragma unroll
            for (int n = 0; n < 4; ++n) {
                int rowb = n * 16 + fr;
                bf[n] = *(const bf16x8*)&Bs[rowb * 64 + ((kk * 4 + fq) ^ (rowb & 7)) * 8];
            }
            #pragma unroll
            for (int m = 0; m < 2; ++m)
                #pragma unroll
                for (int n = 0; n < 4; ++n)
                    acc[m][n] = __builtin_amdgcn_mfma_f32_16x16x32_bf16(af[m], bf[n], acc[m][n], 0, 0, 0);
        }
        __syncthreads();
    }

    if (type < 2) {
        unsigned short* P = (type == 0 ? Qb : Kb) + ((size_t)bh * SEQ) * 64;
        #pragma unroll
        for (int m = 0; m < 2; ++m)
            #pragma unroll
            for (int n = 0; n < 4; ++n) {
                int d = n * 16 + fr;
                int fi = d & 31;
                #pragma unroll
                for (int j = 0; j < 4; ++j) {
                    int s = s0 + wave * 32 + m * 16 + fq * 4 + j;
                    float2 cs = rtab[s * 32 + fi];
                    float val = acc[m][n][j], par = acc[m][n ^ 2][j];
                    float o = (d < 32) ? val * cs.x - par * cs.y
                                       : val * cs.x + par * cs.y;
                    P[(size_t)s * 64 + d] = f2bf(o);
                }
            }
    } else {
        // V: LDS transpose (reuse As+Bs region), row stride 136
        unsigned short* vt = As;    // 64*136*2 = 17408 B <= 24576 B
        #pragma unroll
        for (int m = 0; m < 2; ++m)
            #pragma unroll
            for (int n = 0; n < 4; ++n) {
                int d = n * 16 + fr;
                #pragma unroll
                for (int j = 0; j < 4; ++j)
                    vt[d * 136 + wave * 32 + m * 16 + fq * 4 + j] = f2bf(acc[m][n][j]);
            }
        __syncthreads();
        int d = tid >> 2, sg = tid & 3;
        unsigned short* vrow = Vt + ((size_t)bh * 64 + d) * SEQ + s0 + sg * 32;
        #pragma unroll
        for (int i = 0; i < 4; ++i)
            *(bf16x8*)(vrow + i * 8) = *(const bf16x8*)&vt[d * 136 + sg * 32 + i * 8];
    }
}

// ------ fused FFN-in: 128x64 tile, dual B panels, gated GELU out ---------
__global__ __launch_bounds__(256) void gemm_ffn128(const unsigned short* __restrict__ A,
                                                   const unsigned short* __restrict__ B0t,
                                                   const unsigned short* __restrict__ B1t,
                                                   unsigned short* __restrict__ O) {
    __shared__ unsigned short As[128 * 64];   // 16 KB
    __shared__ unsigned short Bs0[64 * 64];   // 8 KB
    __shared__ unsigned short Bs1[64 * 64];   // 8 KB
    int bid = blockIdx.x;                      // 576 blocks
    int id2 = (bid & 7) * 72 + (bid >> 3);
    int col0 = (id2 % 18) * 64, row0 = (id2 / 18) * 128;
    int tid = threadIdx.x;
    int wave = tid >> 6, lane = tid & 63;
    int fr = lane & 15, fq = lane >> 4;

    f32x4 acc0[2][4], acc1[2][4];
    #pragma unroll
    for (int m = 0; m < 2; ++m)
        #pragma unroll
        for (int n = 0; n < 4; ++n) {
            acc0[m][n] = (f32x4){0.f, 0.f, 0.f, 0.f};
            acc1[m][n] = (f32x4){0.f, 0.f, 0.f, 0.f};
        }

    const size_t strideA = (size_t)768 * 2;
    const char* Ab  = (const char*)A;
    const char* B0b = (const char*)B0t;
    const char* B1b = (const char*)B1t;

    for (int k0 = 0; k0 < 768; k0 += 64) {
        #pragma unroll
        for (int r = 0; r < 4; ++r) {
            int L = r * 4096 + tid * 16;
            int row = L >> 7;
            int ss = ((L >> 4) & 7) ^ (row & 7);
            gload16(Ab + (size_t)(row0 + row) * strideA + (size_t)k0 * 2 + ss * 16,
                    (char*)As + L);
        }
        #pragma unroll
        for (int r = 0; r < 2; ++r) {
            int L = r * 4096 + tid * 16;
            int row = L >> 7;
            int ss = ((L >> 4) & 7) ^ (row & 7);
            size_t goff = (size_t)(col0 + row) * strideA + (size_t)k0 * 2 + ss * 16;
            gload16(B0b + goff, (char*)Bs0 + L);
            gload16(B1b + goff, (char*)Bs1 + L);
        }
        __syncthreads();
        #pragma unroll
        for (int kk = 0; kk < 2; ++kk) {
            bf16x8 af[2], b0[4], b1[4];
            #pragma unroll
            for (int m = 0; m < 2; ++m) {
                int rowa = wave * 32 + m * 16 + fr;
                af[m] = *(const bf16x8*)&As[rowa * 64 + ((kk * 4 + fq) ^ (rowa & 7)) * 8];
            }
            #pragma unroll
            for (int n = 0; n < 4; ++n) {
                int rowb = n * 16 + fr;
                int sl = ((kk * 4 + fq) ^ (rowb & 7)) * 8;
                b0[n] = *(const bf16x8*)&Bs0[rowb * 64 + sl];
                b1[n] = *(const bf16x8*)&Bs1[rowb * 64 + sl];
            }
            #pragma unroll
            for (int m = 0; m < 2; ++m)
                #pragma unroll
                for (int n = 0; n < 4; ++n) {
                    acc0[m][n] = __builtin_amdgcn_mfma_f32_16x16x32_bf16(af[m], b0[n], acc0[m][n], 0, 0, 0);
                    acc1[m][n] = __builtin_amdgcn_mfma_f32_16x16x32_bf16(af[m], b1[n], acc1[m][n], 0, 0, 0);
                }
        }
        __syncthreads();
    }

    #pragma unroll
    for (int m = 0; m < 2; ++m)
        #pragma unroll
        for (int n = 0; n < 4; ++n)
            #pragma unroll
            for (int j = 0; j < 4; ++j) {
                int r = row0 + wave * 32 + m * 16 + fq * 4 + j;
                float xa = acc0[m][n][j];
                float tn = tanhf(0.7978845608028654f * (xa + 0.044715f * xa * xa * xa));
                float gv = 0.5f * xa * (1.f + tn) * acc1[m][n][j];
                O[(size_t)r * INTER + col0 + n * 16 + fr] = f2bf(gv);
            }
}

// ---------------- MFMA sliding-window attention ---------------------------
__global__ __launch_bounds__(256) void attn_mfma(const unsigned short* __restrict__ Qb,
                                                 const unsigned short* __restrict__ Kb,
                                                 const unsigned short* __restrict__ Vt,
                                                 const int* __restrict__ pmask,
                                                 unsigned short* __restrict__ ao) {
    __shared__ unsigned short Ks[KTA * 64];
    __shared__ unsigned short Vs[64 * KTA];
    __shared__ unsigned short Ps[4][16 * KTA];
    __shared__ float pmsk[KTA];

    int bid = blockIdx.x;
    int qt = bid & 31;
    int h  = (bid >> 5) % NHEADS;
    int b  = bid / (32 * NHEADS);
    int bh = b * NHEADS + h;
    int q0 = qt * QTA;
    int kstart = q0 - 64;
    int tid = threadIdx.x;
    int wave = tid >> 6, lane = tid & 63;
    int fr = lane & 15, fq = lane >> 4;

    const unsigned short* Kg = Kb + ((size_t)bh * SEQ) * 64;
    const unsigned short* Vg = Vt + ((size_t)bh * 64) * SEQ;

    if (tid < KTA) {
        int k = kstart + tid;
        pmsk[tid] = (k >= 0 && k < SEQ) ? (1.0f - (float)pmask[b * SEQ + k]) * -1e9f
                                        : -1e9f;
    }

    bool interior = (qt != 0) && (qt != 31);
    if (interior) {
        #pragma unroll
        for (int r = 0; r < 6; ++r) {
            int c = r * 256 + tid;
            int row = c >> 3, slot = c & 7;
            int ss = slot ^ (row & 7);
            gload16(Kg + (size_t)(kstart + row) * 64 + ss * 8, (char*)Ks + c * 16);
        }
        #pragma unroll
        for (int r = 0; r < 6; ++r) {
            int c = r * 256 + tid;
            int d = c / 24, slot = c - d * 24;
            int ss = (slot & ~7) | ((slot & 7) ^ (d & 7));
            gload16(Vg + (size_t)d * SEQ + kstart + ss * 8, (char*)Vs + c * 16);
        }
    } else {
        #pragma unroll
        for (int r = 0; r < 6; ++r) {
            int c = r * 256 + tid;
            int row = c >> 3, slot = c & 7;
            int ss = slot ^ (row & 7);
            int sk = kstart + row;
            bf16x8 val = {0, 0, 0, 0, 0, 0, 0, 0};
            if (sk >= 0 && sk < SEQ)
                val = *(const bf16x8*)(Kg + (size_t)sk * 64 + ss * 8);
            *(bf16x8*)((char*)Ks + c * 16) = val;
        }
        #pragma unroll
        for (int r = 0; r < 6; ++r) {
            int c = r * 256 + tid;
            int d = c / 24, slot = c - d * 24;
            int ss = (slot & ~7) | ((slot & 7) ^ (d & 7));
            int start = kstart + ss * 8;
            bf16x8 val = {0, 0, 0, 0, 0, 0, 0, 0};
            if (start >= 0 && start + 8 <= SEQ)
                val = *(const bf16x8*)(Vg + (size_t)d * SEQ + start);
            *(bf16x8*)((char*)Vs + c * 16) = val;
        }
    }
    __syncthreads();

    const unsigned short* Qg = Qb + ((size_t)bh * SEQ + q0 + wave * 16 + fr) * 64 + fq * 8;
    bf16x8 qf0 = *(const bf16x8*)(Qg);
    bf16x8 qf1 = *(const bf16x8*)(Qg + 32);

    f32x4 sc[12];
    #pragma unroll
    for (int n = 0; n < 12; ++n) sc[n] = (f32x4){0.f, 0.f, 0.f, 0.f};
    #pragma unroll
    for (int n = 0; n < 12; ++n) {
        int row = n * 16 + fr;
        int base = row * 64;
        bf16x8 k0 = *(const bf16x8*)&Ks[base + ((fq)     ^ (row & 7)) * 8];
        bf16x8 k1 = *(const bf16x8*)&Ks[base + ((4 + fq) ^ (row & 7)) * 8];
        sc[n] = __builtin_amdgcn_mfma_f32_16x16x32_bf16(qf0, k0, sc[n], 0, 0, 0);
        sc[n] = __builtin_amdgcn_mfma_f32_16x16x32_bf16(qf1, k1, sc[n], 0, 0, 0);
    }

    int qrow_base = q0 + wave * 16 + fq * 4;
    float mj[4] = {-1e30f, -1e30f, -1e30f, -1e30f}, sj[4];
    #pragma unroll
    for (int n = 0; n < 12; ++n) {
        int k = kstart + n * 16 + fr;
        float pm = pmsk[n * 16 + fr];
        #pragma unroll
        for (int j = 0; j < 4; ++j) {
            int diff = qrow_base + j - k;
            float s = sc[n][j] * 0.125f + pm;
            if (diff > 64 || diff < -64) s = -1e30f;
            sc[n][j] = s;
            mj[j] = fmaxf(mj[j], s);
        }
    }
    #pragma unroll
    for (int j = 0; j < 4; ++j) {
        #pragma unroll
        for (int mk = 1; mk < 16; mk <<= 1)
            mj[j] = fmaxf(mj[j], __shfl_xor(mj[j], mk, 16));
        sj[j] = 0.f;
    }
    #pragma unroll
    for (int n = 0; n < 12; ++n)
        #pragma unroll
        for (int j = 0; j < 4; ++j) {
            float e = expf(sc[n][j] - mj[j]);
            sc[n][j] = e;
            sj[j] += e;
        }
    #pragma unroll
    for (int j = 0; j < 4; ++j)
        #pragma unroll
        for (int mk = 1; mk < 16; mk <<= 1)
            sj[j] += __shfl_xor(sj[j], mk, 16);

    unsigned short* Pw = Ps[wave];
    #pragma unroll
    for (int n = 0; n < 12; ++n) {
        int slot = n * 2 + (fr >> 3);
        #pragma unroll
        for (int j = 0; j < 4; ++j) {
            int row = fq * 4 + j;
            int ss = (slot & ~7) | ((slot & 7) ^ (row & 7));
            Pw[row * KTA + ss * 8 + (fr & 7)] = f2bf(sc[n][j]);
        }
    }

    f32x4 oacc[4];
    #pragma unroll
    for (int n = 0; n < 4; ++n) oacc[n] = (f32x4){0.f, 0.f, 0.f, 0.f};
    #pragma unroll
    for (int kt = 0; kt < 6; ++kt) {
        int slot = kt * 4 + fq;
        int ssp = (slot & ~7) | ((slot & 7) ^ (fr & 7));
        bf16x8 pa = *(const bf16x8*)&Pw[fr * KTA + ssp * 8];
        #pragma unroll
        for (int n = 0; n < 4; ++n) {
            int d = n * 16 + fr;
            int ssv = (slot & ~7) | ((slot & 7) ^ (d & 7));
            bf16x8 vf = *(const bf16x8*)&Vs[d * KTA + ssv * 8];
            oacc[n] = __builtin_amdgcn_mfma_f32_16x16x32_bf16(pa, vf, oacc[n], 0, 0, 0);
        }
    }

    unsigned short* aob = ao + ((size_t)(b * SEQ + qrow_base)) * HID + h * 64;
    float rs[4];
    #pragma unroll
    for (int j = 0; j < 4; ++j) rs[j] = 1.0f / sj[j];
    #pragma unroll
    for (int n = 0; n < 4; ++n)
        #pragma unroll
        for (int j = 0; j < 4; ++j)
            aob[(size_t)j * HID + n * 16 + fr] = f2bf(oacc[n][j] * rs[j]);
}

extern "C" void kernel_launch(void* const* d_in, const int* in_sizes, int n_in,
                              void* d_out, int out_size, void* d_ws, size_t ws_size,
                              hipStream_t stream) {
    const float* x       = (const float*)d_in[0];
    const int*   pmask   = (const int*)d_in[1];
    const float* wqkv    = (const float*)d_in[2];
    const float* wo_attn = (const float*)d_in[3];
    const float* wi0     = (const float*)d_in[4];
    const float* wi1     = (const float*)d_in[5];
    const float* wo_mlp  = (const float*)d_in[6];
    const float* g_attn  = (const float*)d_in[7];
    const float* g_mlp   = (const float*)d_in[8];
    float* out = (float*)d_out;

    char* w = (char*)d_ws;
    unsigned short* hbf   = (unsigned short*)(w);              // 6291456 B
    unsigned short* aobf  = (unsigned short*)(w + 6291456);    // 6291456 B
    unsigned short* Qb    = (unsigned short*)(w + 12582912);   // 6291456 B
    unsigned short* Kb    = (unsigned short*)(w + 18874368);   // 6291456 B
    unsigned short* Vt    = (unsigned short*)(w + 25165824);   // 6291456 B
    unsigned short* mgate = (unsigned short*)(w + 31457280);   // 9437184 B
    float2*         rtab  = (float2*)(w + 40894464);           // 524288 B
    unsigned short* wqkvT = (unsigned short*)(w + 41418752);   // [2304][768]
    unsigned short* woaT  = (unsigned short*)(w + 44957696);   // [768][768]
    unsigned short* wi0T  = (unsigned short*)(w + 46137344);   // [1152][768]
    unsigned short* wi1T  = (unsigned short*)(w + 47906816);   // [1152][768]
    unsigned short* womT  = (unsigned short*)(w + 49676288);   // [768][1152]

    // 0. merged prep: 5 weight transposes + rope table (one launch)
    prep_kernel<<<5152, 256, 0, stream>>>(wqkv, wo_attn, wi0, wi1, wo_mlp,
                                          wqkvT, woaT, wi0T, wi1T, womT, rtab);
    // 1. h = rmsnorm(x, g_attn)
    rmsnorm_kernel<<<ROWS, 256, 0, stream>>>(x, g_attn, hbf);
    // 2. fused qkv GEMM + RoPE + layout -> Qb, Kb, Vt
    gemm_qkv128<<<1152, 256, 0, stream>>>(hbf, wqkvT, rtab, Qb, Kb, Vt);
    // 3. MFMA sliding-window attention
    attn_mfma<<<NB * NHEADS * (SEQ / QTA), 256, 0, stream>>>(Qb, Kb, Vt, pmask, aobf);
    // 4. x1 = x + ao @ wo_attn  -> d_out
    mfma_gemm64<<<768, 256, 0, stream>>>(aobf, woaT, x, out, 768, 768, 12);
    // 5. h = rmsnorm(x1, g_mlp)
    rmsnorm_kernel<<<ROWS, 256, 0, stream>>>(out, g_mlp, hbf);
    // 6. mgate = gelu(h@wi0) * (h@wi1)  (fused, bf16 out)
    gemm_ffn128<<<576, 256, 0, stream>>>(hbf, wi0T, wi1T, mgate);
    // 7. out = x1 + mgate @ wo_mlp
    mfma_gemm64<<<768, 256, 0, stream>>>(mgate, womT, out, out, 768, 1152, 12);
}